// Round 7
// baseline (329.791 us; speedup 1.0000x reference)
//
#include <hip/hip_runtime.h>

typedef unsigned short u16;
typedef unsigned int u32;
typedef __bf16 bf16x8 __attribute__((ext_vector_type(8)));
typedef float f32x4 __attribute__((ext_vector_type(4)));

#define BB   4
#define TT   1024
#define CDIM 2048
#define NH   16
#define NKV  4
#define HDIM 128

__device__ __forceinline__ float b2f(u16 u) {
    union { u32 i; float f; } x; x.i = ((u32)u) << 16; return x.f;
}
__device__ __forceinline__ u16 f2b(float f) {
    union { float f; u32 i; } x; x.f = f;
    u32 r = (x.i + 0x7fffu + ((x.i >> 16) & 1u)) >> 16;
    return (u16)r;
}
__device__ __forceinline__ void async16(const void* g, void* l) {
    __builtin_amdgcn_global_load_lds((const __attribute__((address_space(1))) void*)g,
                                     (__attribute__((address_space(3))) void*)l, 16, 0, 0);
}

// Inline dtype probe: every wave samples the same 64 even u16s of x (low
// mantissa halves if fp32 -> uniform-random exponents -> ~72% implausible;
// real bf16 N(0,1) -> ~0%). Ballot => identical wave-uniform verdict everywhere.
__device__ __forceinline__ bool wave_is_f32(const u16* xp) {
    u16 v = xp[(threadIdx.x & 63) * 2];
    int e = (v >> 7) & 0xFF;
    bool bad = (v != 0) && (e < 90 || e > 160);
    return __popcll(__ballot(bad)) > 16;
}

// ---------------------------------------------------------------------------
// Fused pre-pass: convert x, cos, sin to bf16 + all three weight transposes.
// Block ranges: [0,8192) x | [8192,8256) cos | [8256,8320) sin | [8320,10880) W.
// ---------------------------------------------------------------------------
__global__ __launch_bounds__(256) void pre_k(const void* __restrict__ x,
                                             const void* __restrict__ Wq,
                                             const void* __restrict__ Wkv,
                                             const void* __restrict__ Wo,
                                             u16* __restrict__ xb,
                                             u16* __restrict__ csb,
                                             u16* __restrict__ snb,
                                             u16* __restrict__ WqkvT,
                                             u16* __restrict__ WoT,
                                             const void* __restrict__ cs,
                                             const void* __restrict__ sn) {
    const bool f32m = wave_is_f32((const u16*)x);
    int bid = blockIdx.x;
    if (bid < 8320) {                        // element-wise conversions
        const void* src; u16* dst; int i;
        if (bid < 8192)      { src = x;  dst = xb;  i = bid * 256 + threadIdx.x; }
        else if (bid < 8256) { src = cs; dst = csb; i = (bid - 8192) * 256 + threadIdx.x; }
        else                 { src = sn; dst = snb; i = (bid - 8256) * 256 + threadIdx.x; }
        union { u16 u[4]; ushort4 v; } o;
        if (f32m) {
            float4 f = ((const float4*)src)[i];
            o.u[0] = f2b(f.x); o.u[1] = f2b(f.y); o.u[2] = f2b(f.z); o.u[3] = f2b(f.w);
        } else {
            o.v = ((const ushort4*)src)[i];
        }
        ((ushort4*)dst)[i] = o.v;
        return;
    }
    // weight transpose: WT[c][r] = bf16(W[r][c])
    __shared__ alignas(16) u16 tile[64 * 65];
    int t = bid - 8320;
    const void* W; u16* WT; int rows, cols, bx, by;
    if (t < 1024)      { W = Wq;  WT = WqkvT;                    rows = 2048; cols = 2048; bx = t & 31;  by = t >> 5; }
    else if (t < 1536) { int l = t - 1024; W = Wkv; WT = WqkvT + (long)2048 * 2048; rows = 2048; cols = 1024; bx = l & 15; by = l >> 4; }
    else               { int l = t - 1536; W = Wo;  WT = WoT;  rows = 2048; cols = 2048; bx = l & 31;   by = l >> 5; }
    const int r0 = by * 64, c0 = bx * 64;
#pragma unroll
    for (int i = 0; i < 16; i++) {
        int c = threadIdx.x + i * 256;
        int rr = c >> 6, cc = c & 63;
        long idx = (long)(r0 + rr) * cols + c0 + cc;
        tile[rr * 65 + cc] = f32m ? f2b(((const float*)W)[idx]) : ((const u16*)W)[idx];
    }
    __syncthreads();
#pragma unroll
    for (int i = 0; i < 16; i++) {
        int c = threadIdx.x + i * 256;
        int rr = c >> 6, cc = c & 63;
        WT[(long)(c0 + rr) * rows + r0 + cc] = tile[cc * 65 + rr];
    }
}

// ---------------------------------------------------------------------------
// m201-faithful 256x256 8-phase bf16 GEMM: C[m][n] = sum_k A[m][k]*Bt[n][k].
// 512 thr = 8 waves (2M x 4N), BK=64, LDS 128 KiB = 2 buf x 2 half x
// (A,B) x 128x64. K-loop UNROLLED x2 (2 K-tiles/iter, compile-time buffer
// indices -> immediate-offset ds_reads). Per phase:
//   {ds_read subtile; stage 1 half-tile (2 gload_lds); [lgkm(8) if 12 rds];
//    BAR; lgkm(0); setprio(1); 16 MFMA; setprio(0); BAR}
// NO sched_barrier (m141: order-pinning regresses). Overlap mechanism:
// a wave ARRIVES at the post-MFMA barrier after ISSUING its MFMAs; the next
// phase's ds_reads issue under the MFMA drain.
// Staging stream (half-tile = 128 rows x 64 cols, 2 loads/thread):
//   p0: B-hi(t+1)->nxt | p1: A-hi(t+1)->nxt | p2: B-lo(t+2)->cur |
//   p3: A-lo(t+2)->cur, then vmcnt(4) once per K-tile (retires exactly
//   tile t+1's 4 halves, keeps t+2's 2 staged halves in flight; never 0
//   in steady state).
// WAR: B[cur] halves last read at p1's lgkm(0) -> overwrite at p2 is >=1
// barrier later; A[cur] at p2's lgkm(0) -> overwrite at p3; nxt's halves
// retired a full tile earlier. RAW: tile t+1 fully retired by (t)'s
// vmcnt(4) which precedes p3's closing barrier.
// Swizzle: 16B-chunk ^= (row&7); global source pre-swizzled, LDS dest
// linear (rule #21); 0 bank conflicts measured across R1-R6.
// ---------------------------------------------------------------------------
__global__ __launch_bounds__(512, 2) void gemm256(const u16* __restrict__ A,
                                                  const u16* __restrict__ Bt,
                                                  void* __restrict__ C,
                                                  int N, int Kd,
                                                  const u16* __restrict__ xprobe) {
    __shared__ alignas(16) u16 As[2][2][128 * 64];   // [buf][half]
    __shared__ alignas(16) u16 Bs[2][2][128 * 64];
    const bool f32m = (xprobe != nullptr) && wave_is_f32(xprobe);
    const int tid = threadIdx.x;
    const int w = tid >> 6, lane = tid & 63;
    const int wm = w >> 2, wn = w & 3;
    const int l16 = lane & 15, quad = lane >> 4;
    const long arow0 = (long)blockIdx.y * 256;
    const long brow0 = (long)blockIdx.x * 256;
    const int NT = Kd >> 6;                  // even (32) for both GEMMs

    // staging: half-tile = 1024 16B-chunks; thread covers {tid, tid+512}.
    long gs0, gs1; int lo0, lo1;
    {
        int ch = tid, r = ch >> 3, cp = ch & 7;
        gs0 = (long)r * Kd + ((cp ^ (r & 7)) << 3);
        lo0 = ch << 3;
        ch = tid + 512; r = ch >> 3; cp = ch & 7;
        gs1 = (long)r * Kd + ((cp ^ (r & 7)) << 3);
        lo1 = ch << 3;
    }
    const u16* Ab = A + arow0 * Kd;
    const u16* Bb = Bt + brow0 * Kd;
    const long halfK = 128L * Kd;

#define STAGEH(ldsbase, gbase) do {        \
        const u16* _g = (gbase);           \
        u16* _l = (ldsbase);               \
        async16(_g + gs0, _l + lo0);       \
        async16(_g + gs1, _l + lo1); } while (0)
#define BARRIER() asm volatile("s_barrier" ::: "memory")
#define LGKM0()   asm volatile("s_waitcnt lgkmcnt(0)" ::: "memory")
#define LGKM8()   asm volatile("s_waitcnt lgkmcnt(8)" ::: "memory")

    // fragment read offsets within a half (u16 units); row&7 == l16&7.
    const int sw = l16 & 7;
    int aoff[2], boff[2];
    aoff[0] = l16 * 64 + ((quad ^ sw) << 3);
    aoff[1] = l16 * 64 + (((4 + quad) ^ sw) << 3);
    boff[0] = ((wn & 1) * 64 + l16) * 64 + ((quad ^ sw) << 3);
    boff[1] = ((wn & 1) * 64 + l16) * 64 + (((4 + quad) ^ sw) << 3);
    const int bh = wn >> 1;                  // wave's B half

    f32x4 acc[8][4];
#pragma unroll
    for (int i = 0; i < 8; i++)
#pragma unroll
        for (int j = 0; j < 4; j++) acc[i][j] = {0.f, 0.f, 0.f, 0.f};

    bf16x8 afLo[4][2], afHi[4][2], bfA[2][2], bfB[2][2];

    // prologue: tile0 (4 halves) + tile1 {B-lo, A-lo}; vmcnt(4) retires
    // tile0, keeps tile1's 2 staged halves in flight (steady-state shape).
    STAGEH(&Bs[0][0][0], Bb);
    STAGEH(&Bs[0][1][0], Bb + halfK);
    STAGEH(&As[0][0][0], Ab);
    STAGEH(&As[0][1][0], Ab + halfK);
    STAGEH(&Bs[1][0][0], Bb + 64);
    STAGEH(&As[1][0][0], Ab + 64);
    asm volatile("s_waitcnt vmcnt(4)" ::: "memory");
    BARRIER();

#define KTILE(T, CUR, NXT)                                                      \
    {                                                                           \
        const u16* pA = &As[CUR][wm][0];                                        \
        const u16* pB = &Bs[CUR][bh][0];                                        \
        /* ---- p0: read afLo+bfA (12); stage B-hi(T+1); q0 ---- */             \
        _Pragma("unroll")                                                       \
        for (int ks = 0; ks < 2; ks++) {                                        \
            _Pragma("unroll")                                                   \
            for (int mt = 0; mt < 4; mt++)                                      \
                afLo[mt][ks] = *(const bf16x8*)&pA[aoff[ks] + mt * 1024];       \
            _Pragma("unroll")                                                   \
            for (int nt = 0; nt < 2; nt++)                                      \
                bfA[nt][ks] = *(const bf16x8*)&pB[boff[ks] + nt * 1024];        \
        }                                                                       \
        if ((T) + 1 < NT) STAGEH(&Bs[NXT][1][0], Bb + halfK + ((T) + 1) * 64);  \
        LGKM8();                                                                \
        BARRIER();                                                              \
        LGKM0();                                                                \
        __builtin_amdgcn_s_setprio(1);                                          \
        _Pragma("unroll")                                                       \
        for (int ks = 0; ks < 2; ks++)                                          \
            _Pragma("unroll")                                                   \
            for (int mt = 0; mt < 4; mt++)                                      \
                _Pragma("unroll")                                               \
                for (int nt = 0; nt < 2; nt++)                                  \
                    acc[mt][nt] = __builtin_amdgcn_mfma_f32_16x16x32_bf16(      \
                        afLo[mt][ks], bfA[nt][ks], acc[mt][nt], 0, 0, 0);       \
        __builtin_amdgcn_s_setprio(0);                                          \
        BARRIER();                                                              \
        /* ---- p1: read bfB (4); stage A-hi(T+1); q1 ---- */                   \
        _Pragma("unroll")                                                       \
        for (int ks = 0; ks < 2; ks++)                                          \
            _Pragma("unroll")                                                   \
            for (int nt = 0; nt < 2; nt++)                                      \
                bfB[nt][ks] = *(const bf16x8*)&pB[boff[ks] + (nt + 2) * 1024];  \
        if ((T) + 1 < NT) STAGEH(&As[NXT][1][0], Ab + halfK + ((T) + 1) * 64);  \
        BARRIER();                                                              \
        LGKM0();                                                                \
        __builtin_amdgcn_s_setprio(1);                                          \
        _Pragma("unroll")                                                       \
        for (int ks = 0; ks < 2; ks++)                                          \
            _Pragma("unroll")                                                   \
            for (int mt = 0; mt < 4; mt++)                                      \
                _Pragma("unroll")                                               \
                for (int nt = 0; nt < 2; nt++)                                  \
                    acc[mt][nt + 2] = __builtin_amdgcn_mfma_f32_16x16x32_bf16(  \
                        afLo[mt][ks], bfB[nt][ks], acc[mt][nt + 2], 0, 0, 0);   \
        __builtin_amdgcn_s_setprio(0);                                          \
        BARRIER();                                                              \
        /* ---- p2: read afHi (8); stage B-lo(T+2); q2 ---- */                  \
        _Pragma("unroll")                                                       \
        for (int ks = 0; ks < 2; ks++)                                          \
            _Pragma("unroll")                                                   \
            for (int mt = 0; mt < 4; mt++)                                      \
                afHi[mt][ks] = *(const bf16x8*)&pA[aoff[ks] + (mt + 4) * 1024]; \
        if ((T) + 2 < NT) STAGEH(&Bs[CUR][0][0], Bb + ((T) + 2) * 64);          \
        BARRIER();                                                              \
        LGKM0();                                                                \
        __builtin_amdgcn_s_setprio(1);                                          \
        _Pragma("unroll")                                                       \
        for (int ks = 0; ks < 2; ks++)                                          \
            _Pragma("unroll")                                                   \
            for (int mt = 0; mt < 4; mt++)                                      \
                _Pragma("unroll")                                               \
                for (int nt = 0; nt < 2; nt++)                                  \
                    acc[mt + 4][nt + 2] = __builtin_amdgcn_mfma_f32_16x16x32_bf16( \
                        afHi[mt][ks], bfB[nt][ks], acc[mt + 4][nt + 2], 0, 0, 0);  \
        __builtin_amdgcn_s_setprio(0);                                          \
        BARRIER();                                                              \
        /* ---- p3: stage A-lo(T+2); q3; vmcnt(4) once per K-tile ---- */       \
        if ((T) + 2 < NT) STAGEH(&As[CUR][0][0], Ab + ((T) + 2) * 64);          \
        BARRIER();                                                              \
        __builtin_amdgcn_s_setprio(1);                                          \
        _Pragma("unroll")                                                       \
        for (int ks = 0; ks < 2; ks++)                                          \
            _Pragma("unroll")                                                   \
            for (int mt = 0; mt < 4; mt++)                                      \
                _Pragma("unroll")                                               \
                for (int nt = 0; nt < 2; nt++)                                  \
                    acc[mt + 4][nt] = __builtin_amdgcn_mfma_f32_16x16x32_bf16(  \
                        afHi[mt][ks], bfA[nt][ks], acc[mt + 4][nt], 0, 0, 0);   \
        __builtin_amdgcn_s_setprio(0);                                          \
        if ((T) + 1 < NT) {                                                     \
            if ((T) + 2 < NT) asm volatile("s_waitcnt vmcnt(4)" ::: "memory");  \
            else              asm volatile("s_waitcnt vmcnt(0)" ::: "memory");  \
        }                                                                       \
        BARRIER();                                                              \
    }

#pragma unroll 1
    for (int t = 0; t < NT; t += 2) {
        KTILE(t, 0, 1);
        KTILE(t + 1, 1, 0);
    }
#undef KTILE
#undef STAGEH
#undef BARRIER
#undef LGKM0
#undef LGKM8

    // epilogue: rows wm*128+mt*16+quad*4+r, cols wn*64+nt*16+l16
#pragma unroll
    for (int mt = 0; mt < 8; mt++) {
#pragma unroll
        for (int nt = 0; nt < 4; nt++) {
            long col = brow0 + wn * 64 + nt * 16 + l16;
#pragma unroll
            for (int r = 0; r < 4; r++) {
                long row = arow0 + wm * 128 + mt * 16 + quad * 4 + r;
                if (f32m) ((float*)C)[row * N + col] = acc[mt][nt][r];
                else      ((u16*)C)[row * N + col] = f2b(acc[mt][nt][r]);
            }
        }
    }
}

// ---------------------------------------------------------------------------
// RoPE(Q), RoPE(K), V-transpose in one dispatch, split by block ranges.
// ---------------------------------------------------------------------------
__global__ __launch_bounds__(256) void prep_k(const u16* __restrict__ QKVraw,
                                              const u16* __restrict__ cs,
                                              const u16* __restrict__ sn,
                                              u16* __restrict__ Qr,
                                              u16* __restrict__ Kr,
                                              u16* __restrict__ Vt) {
    int bid = blockIdx.x;
    if (bid < 16384) {                       // RoPE Q -> (B,H,T,HD)
        int idx = bid * 256 + threadIdx.x;
        int d = idx & 63;
        int t = (idx >> 6) & (TT - 1);
        int bh = idx >> 16;
        long src = ((long)((bh >> 4) * TT + t)) * 3072 + (bh & 15) * HDIM;
        float u1 = b2f(QKVraw[src + d]), u2 = b2f(QKVraw[src + d + 64]);
        float c = b2f(cs[t * 64 + d]), s = b2f(sn[t * 64 + d]);
        long dst = ((long)bh * TT + t) * HDIM;
        Qr[dst + d] = f2b(u1 * c - u2 * s);
        Qr[dst + d + 64] = f2b(u1 * s + u2 * c);
    } else if (bid < 20480) {                // RoPE K -> (B,KVH,T,HD)
        int idx = (bid - 16384) * 256 + threadIdx.x;
        int d = idx & 63;
        int t = (idx >> 6) & (TT - 1);
        int bk = idx >> 16;
        long src = ((long)((bk >> 2) * TT + t)) * 3072 + 2048 + (bk & 3) * HDIM;
        float u1 = b2f(QKVraw[src + d]), u2 = b2f(QKVraw[src + d + 64]);
        float c = b2f(cs[t * 64 + d]), s = b2f(sn[t * 64 + d]);
        long dst = ((long)bk * TT + t) * HDIM;
        Kr[dst + d] = f2b(u1 * c - u2 * s);
        Kr[dst + d + 64] = f2b(u1 * s + u2 * c);
    } else {                                 // V -> (B,KVH,HD,T)
        int idx = (bid - 20480) * 256 + threadIdx.x;
        int t = idx & (TT - 1);
        int d = (idx >> 10) & (HDIM - 1);
        int bk = idx >> 17;
        Vt[idx] = QKVraw[((long)(bk >> 2) * TT + t) * 3072 + 2560 + (bk & 3) * HDIM + d];
    }
}

// ---------------------------------------------------------------------------
// Flash attention v5: balanced persistent pairs + double-buffered K/V with
// fine-grained vmcnt (loads stay in flight across compute; vmcnt(0) never
// runs inside the K-loop). 1024 items (bh, qt) sorted heavy-first; block b
// does items {b, 1023-b} => exactly 17 tile-iterations per block; grid 512
// = 2 blocks/CU resident (LDS 75KB). Compute per tile identical to R4/R6
// (verified): S^T = K·Q^T, in-lane online softmax, Ps LDS hop, O^T = V^T·P^T.
// ---------------------------------------------------------------------------
__global__ __launch_bounds__(256) void attn_kernel(const u16* __restrict__ Q,
                                                   const u16* __restrict__ Kr,
                                                   const u16* __restrict__ Vt,
                                                   u16* __restrict__ O) {
    __shared__ alignas(16) u16 Ks[2][64 * 128];   // [t][d], chunk ^= row&7 (bit3 kept)
    __shared__ alignas(16) u16 Vts[2][128 * 64];  // [d][t], chunk ^= row&7
    __shared__ alignas(16) u16 Ps[64 * 88];       // [q][k], per-wave rows only

    const int tid = threadIdx.x, w = tid >> 6, lane = tid & 63;
    const int l16 = lane & 15, quad = lane >> 4;
    const float scale2 = 0.08838834764831845f * 1.4426950408889634f; // 1/sqrt(128)*log2e

#pragma unroll 1
    for (int it = 0; it < 2; it++) {
        const int j = it ? (1023 - (int)blockIdx.x) : (int)blockIdx.x;
        const int qt = 15 - (j >> 6);        // heavy first for it==0
        const int bh = j & 63;
        const int b = bh >> 4, h = bh & 15;
        const int kvh = h >> 2;
        const long qrow0 = (long)bh * TT + qt * 64;
        const long krow0 = (long)(b * NKV + kvh) * TT;
        const long vbase = ((long)(b * NKV + kvh) * HDIM) * TT;

        __syncthreads();  // prior item's LDS reads done; full drain

        // ---- stage this wave's 16 Q rows through Ks[0] (own slots only) ----
#pragma unroll
        for (int i = 0; i < 4; i++) {
            int slot0 = (w * 4 + i) * 64;
            int slot = slot0 + lane;
            int row = slot >> 4, cp = slot & 15;
            int cg = (cp & 8) | ((cp ^ row) & 7);
            async16(Q + (qrow0 + row) * HDIM + cg * 8, &Ks[0][slot0 * 8]);
        }
        asm volatile("s_waitcnt vmcnt(0)" ::: "memory");
        bf16x8 qf[4];
        {
            const int Rq = w * 16 + l16;
#pragma unroll
            for (int ds = 0; ds < 4; ds++) {
                int c = ds * 4 + quad;
                qf[ds] = *(const bf16x8*)&Ks[0][Rq * 128 + ((c & 8) | ((c ^ Rq) & 7)) * 8];
            }
        }
        asm volatile("s_waitcnt lgkmcnt(0)" ::: "memory");  // frags in regs

        // ---- prologue staging: tile0 -> buf0 (overwrites Q, own slots), tile1 -> buf1
#pragma unroll
        for (int i = 0; i < 4; i++) {
            int slot0 = (w * 4 + i) * 64;
            int slot = slot0 + lane;
            int row = slot >> 4, cp = slot & 15;
            int cg = (cp & 8) | ((cp ^ row) & 7);
            async16(Kr + (krow0 + row) * HDIM + cg * 8, &Ks[0][slot0 * 8]);
        }
#pragma unroll
        for (int i = 0; i < 4; i++) {
            int slot0 = (w * 4 + i) * 64;
            int slot = slot0 + lane;
            int row = slot >> 3, cp = slot & 7;
            int cg = cp ^ (row & 7);
            async16(Vt + vbase + (long)row * TT + cg * 8, &Vts[0][slot0 * 8]);
        }
        if (qt >= 1) {
#pragma unroll
            for (int i = 0; i < 4; i++) {
                int slot0 = (w * 4 + i) * 64;
                int slot = slot0 + lane;
                int row = slot >> 4, cp = slot & 15;
                int cg = (cp & 8) | ((cp ^ row) & 7);
                async16(Kr + (krow0 + 64 + row) * HDIM + cg * 8, &Ks[1][slot0 * 8]);
            }
#pragma unroll
            for (int i = 0; i < 4; i++) {
                int slot0 = (w * 4 + i) * 64;
                int slot = slot0 + lane;
                int row = slot >> 3, cp = slot & 7;
                int cg = cp ^ (row & 7);
                async16(Vt + vbase + (long)row * TT + 64 + cg * 8, &Vts[1][slot0 * 8]);
            }
            asm volatile("s_waitcnt vmcnt(8)" ::: "memory");  // tile0 done, tile1 in flight
        } else {
            asm volatile("s_waitcnt vmcnt(0)" ::: "memory");
        }
        asm volatile("s_barrier" ::: "memory");

        f32x4 o[8];
#pragma unroll
        for (int i = 0; i < 8; i++) o[i] = {0.f, 0.f, 0.f, 0.f};
        float m_i = -1.0e30f, l_i = 0.f;
        const int qg = qt * 64 + w * 16 + l16;

#pragma unroll 1
        for (int kt = 0; kt <= qt; kt++) {
            const int cur = kt & 1;
            const u16* ksb = Ks[cur];
            const u16* vsb = Vts[cur];

            // S^T[k][q] = sum_d K[k][d] * Q[q][d]
            f32x4 s[4];
#pragma unroll
            for (int nt = 0; nt < 4; nt++) s[nt] = {0.f, 0.f, 0.f, 0.f};
#pragma unroll
            for (int ds = 0; ds < 4; ds++) {
                int c = ds * 4 + quad;
#pragma unroll
                for (int nt = 0; nt < 4; nt++) {
                    int Rk = nt * 16 + l16;
                    bf16x8 ak = *(const bf16x8*)&ksb[Rk * 128 + ((c & 8) | ((c ^ Rk) & 7)) * 8];
                    s[nt] = __builtin_amdgcn_mfma_f32_16x16x32_bf16(ak, qf[ds], s[nt], 0, 0, 0);
                }
            }

            // online softmax (exp2 domain), in-lane 16 values + 2 shuffles
            float p[4][4];
            float mx = -1.0e30f;
            if (kt == qt) {
#pragma unroll
                for (int nt = 0; nt < 4; nt++)
#pragma unroll
                    for (int r = 0; r < 4; r++) {
                        int kcol = kt * 64 + nt * 16 + quad * 4 + r;
                        float v = (kcol <= qg) ? (float)s[nt][r] * scale2 : -1.0e30f;
                        p[nt][r] = v;
                        mx = fmaxf(mx, v);
                    }
            } else {
#pragma unroll
                for (int nt = 0; nt < 4; nt++)
#pragma unroll
                    for (int r = 0; r < 4; r++) {
                        float v = (float)s[nt][r] * scale2;
                        p[nt][r] = v;
                        mx = fmaxf(mx, v);
                    }
            }
            mx = fmaxf(mx, __shfl_xor(mx, 16));
            mx = fmaxf(mx, __shfl_xor(mx, 32));
            float mnew = fmaxf(m_i, mx);
            float alpha = exp2f(m_i - mnew);
            float rs = 0.f;
#pragma unroll
            for (int nt = 0; nt < 4; nt++)
#pragma unroll
                for (int r = 0; r < 4; r++) {
                    float e = exp2f(p[nt][r] - mnew);
                    p[nt][r] = e;
                    rs += e;
                }
            rs += __shfl_xor(rs, 16);
            rs += __shfl_xor(rs, 32);
            l_i = l_i * alpha + rs;

            // P -> Ps (packed u32, own-wave rows)
            u32* Psw = (u32*)Ps;
            int pb = (w * 16 + l16) * 44 + quad * 2;
#pragma unroll
            for (int nt = 0; nt < 4; nt++) {
                u32 lo = (u32)f2b(p[nt][0]) | ((u32)f2b(p[nt][1]) << 16);
                u32 hi = (u32)f2b(p[nt][2]) | ((u32)f2b(p[nt][3]) << 16);
                Psw[pb + nt * 8]     = lo;
                Psw[pb + nt * 8 + 1] = hi;
            }
            if (__ballot(mnew != m_i) != 0ULL) {
#pragma unroll
                for (int n8 = 0; n8 < 8; n8++)
#pragma unroll
                    for (int r = 0; r < 4; r++) o[n8][r] *= alpha;
            }
            m_i = mnew;

            asm volatile("s_waitcnt lgkmcnt(0)" ::: "memory");  // Ps W->R, same wave

            // O^T[d][q] += V^T[d][k] * P[q][k]
#pragma unroll
            for (int ks = 0; ks < 2; ks++) {
                bf16x8 bp = *(const bf16x8*)&Ps[(w * 16 + l16) * 88 + ks * 32 + quad * 8];
#pragma unroll
                for (int n8 = 0; n8 < 8; n8++) {
                    int Rv = n8 * 16 + l16;
                    int c = ks * 4 + quad;
                    bf16x8 av = *(const bf16x8*)&vsb[Rv * 64 + (c ^ (Rv & 7)) * 8];
                    o[n8] = __builtin_amdgcn_mfma_f32_16x16x32_bf16(av, bp, o[n8], 0, 0, 0);
                }
            }

            if (kt == qt) break;

            // pipeline maintenance: reads of buf[cur] done -> refill it with kt+2
            asm volatile("s_waitcnt lgkmcnt(0)" ::: "memory");  // own ds_reads complete
            asm volatile("s_barrier" ::: "memory");             // all waves done with buf[cur]
            if (kt + 2 <= qt) {
                const int nk = kt + 2;
#pragma unroll
                for (int i = 0; i < 4; i++) {
                    int slot0 = (w * 4 + i) * 64;
                    int slot = slot0 + lane;
                    int row = slot >> 4, cp = slot & 15;
                    int cg = (cp & 8) | ((cp ^ row) & 7);
                    async16(Kr + (krow0 + nk * 64 + row) * HDIM + cg * 8, &Ks[cur][slot0 * 8]);
                }
#pragma unroll
                for (int i = 0; i < 4; i++) {
                    int slot0 = (w * 4 + i) * 64;
                    int slot = slot0 + lane;
                    int row = slot >> 3, cp = slot & 7;
                    int cg = cp ^ (row & 7);
                    async16(Vt + vbase + (long)row * TT + nk * 64 + cg * 8, &Vts[cur][slot0 * 8]);
                }
                asm volatile("s_waitcnt vmcnt(8)" ::: "memory");  // (kt+1)'s loads done
            } else {
                asm volatile("s_waitcnt vmcnt(0)" ::: "memory");
            }
            asm volatile("s_barrier" ::: "memory");  // buf[1-cur] ready across waves
        }

        // epilogue: normalize, pack, store this item's 64 q-rows
        float inv = 1.0f / l_i;
        long obase = ((long)(b * TT + qg)) * CDIM + h * HDIM;
#pragma unroll
        for (int n8 = 0; n8 < 8; n8++) {
            ushort4 st;
            st.x = f2b(o[n8][0] * inv);
            st.y = f2b(o[n8][1] * inv);
            st.z = f2b(o[n8][2] * inv);
            st.w = f2b(o[n8][3] * inv);
            *(ushort4*)&O[obase + n8 * 16 + quad * 4] = st;
        }
    }
}

// ---------------------------------------------------------------------------
extern "C" void kernel_launch(void* const* d_in, const int* in_sizes, int n_in,
                              void* d_out, int out_size, void* d_ws, size_t ws_size,
                              hipStream_t stream) {
    const void* x   = d_in[0];
    const void* Wq  = d_in[1];
    const void* Wkv = d_in[2];
    const void* Wo  = d_in[3];
    const void* cs  = d_in[4];
    const void* sn  = d_in[5];

    char* ws = (char*)d_ws;
    const size_t NEED = 105119748;
    if (ws_size < NEED) return;

    u16* WqkvT = (u16*)(ws + 0);          // 3072x2048 (WqT ++ WkvT)
    u16* WoT   = (u16*)(ws + 12582912);   // 2048x2048
    u16* QKVraw= (u16*)(ws + 20971520);   // 4096x3072
    u16* Qr    = (u16*)(ws + 46137344);   // (B,H,T,HD)
    u16* Kr    = (u16*)(ws + 62914560);   // (B,KVH,T,HD)
    u16* Vt    = (u16*)(ws + 67108864);   // (B,KVH,HD,T)
    u16* ATT   = (u16*)(ws + 71303168);   // 4096x2048
    u16* xb    = (u16*)(ws + 88080384);   // 4096x2048 bf16 x
    u16* csb   = (u16*)(ws + 104857600);  // 1024x64
    u16* snb   = (u16*)(ws + 104988672);  // 1024x64

    pre_k<<<10880, 256, 0, stream>>>(x, Wq, Wkv, Wo, xb, csb, snb, WqkvT, WoT, cs, sn);

    // GEMM1: 4096x3072x2048, 256^2 tiles -> grid 12x16 = 192 WGs
    gemm256<<<dim3(12, 16), 512, 0, stream>>>(xb, WqkvT, QKVraw, 3072, 2048, nullptr);

    prep_k<<<28672, 256, 0, stream>>>(QKVraw, csb, snb, Qr, Kr, Vt);

    attn_kernel<<<512, 256, 0, stream>>>(Qr, Kr, Vt, ATT);

    // GEMM2: 4096x2048x2048, 256^2 tiles -> grid 8x16 = 128 WGs
    gemm256<<<dim3(8, 16), 512, 0, stream>>>(ATT, WoT, d_out, 2048, 2048, (const u16*)x);
}

// Round 8
// 299.465 us; speedup vs baseline: 1.1013x; 1.1013x over previous
//
#include <hip/hip_runtime.h>

typedef unsigned short u16;
typedef unsigned int u32;
typedef __bf16 bf16x8 __attribute__((ext_vector_type(8)));
typedef float f32x4 __attribute__((ext_vector_type(4)));

#define BB   4
#define TT   1024
#define CDIM 2048
#define NH   16
#define NKV  4
#define HDIM 128

__device__ __forceinline__ float b2f(u16 u) {
    union { u32 i; float f; } x; x.i = ((u32)u) << 16; return x.f;
}
__device__ __forceinline__ u16 f2b(float f) {
    union { float f; u32 i; } x; x.f = f;
    u32 r = (x.i + 0x7fffu + ((x.i >> 16) & 1u)) >> 16;
    return (u16)r;
}
__device__ __forceinline__ void async16(const void* g, void* l) {
    __builtin_amdgcn_global_load_lds((const __attribute__((address_space(1))) void*)g,
                                     (__attribute__((address_space(3))) void*)l, 16, 0, 0);
}
template<int N> __device__ __forceinline__ void waitvm() {
    static_assert(N >= 0 && N <= 8, "unsupported vmcnt");
    if constexpr (N == 0)      asm volatile("s_waitcnt vmcnt(0)" ::: "memory");
    else if constexpr (N == 1) asm volatile("s_waitcnt vmcnt(1)" ::: "memory");
    else if constexpr (N == 2) asm volatile("s_waitcnt vmcnt(2)" ::: "memory");
    else if constexpr (N == 3) asm volatile("s_waitcnt vmcnt(3)" ::: "memory");
    else if constexpr (N == 4) asm volatile("s_waitcnt vmcnt(4)" ::: "memory");
    else if constexpr (N == 5) asm volatile("s_waitcnt vmcnt(5)" ::: "memory");
    else if constexpr (N == 6) asm volatile("s_waitcnt vmcnt(6)" ::: "memory");
    else if constexpr (N == 7) asm volatile("s_waitcnt vmcnt(7)" ::: "memory");
    else                       asm volatile("s_waitcnt vmcnt(8)" ::: "memory");
}

// Inline dtype probe: every wave samples the same 64 even u16s of x (low
// mantissa halves if fp32 -> uniform-random exponents -> ~72% implausible;
// real bf16 N(0,1) -> ~0%). Ballot => identical wave-uniform verdict everywhere.
__device__ __forceinline__ bool wave_is_f32(const u16* xp) {
    u16 v = xp[(threadIdx.x & 63) * 2];
    int e = (v >> 7) & 0xFF;
    bool bad = (v != 0) && (e < 90 || e > 160);
    return __popcll(__ballot(bad)) > 16;
}

// ---------------------------------------------------------------------------
// Fused pre-pass: convert x, cos, sin to bf16 + all three weight transposes.
// Block ranges: [0,8192) x | [8192,8256) cos | [8256,8320) sin | [8320,10880) W.
// ---------------------------------------------------------------------------
__global__ __launch_bounds__(256) void pre_k(const void* __restrict__ x,
                                             const void* __restrict__ Wq,
                                             const void* __restrict__ Wkv,
                                             const void* __restrict__ Wo,
                                             u16* __restrict__ xb,
                                             u16* __restrict__ csb,
                                             u16* __restrict__ snb,
                                             u16* __restrict__ WqkvT,
                                             u16* __restrict__ WoT,
                                             const void* __restrict__ cs,
                                             const void* __restrict__ sn) {
    const bool f32m = wave_is_f32((const u16*)x);
    int bid = blockIdx.x;
    if (bid < 8320) {                        // element-wise conversions
        const void* src; u16* dst; int i;
        if (bid < 8192)      { src = x;  dst = xb;  i = bid * 256 + threadIdx.x; }
        else if (bid < 8256) { src = cs; dst = csb; i = (bid - 8192) * 256 + threadIdx.x; }
        else                 { src = sn; dst = snb; i = (bid - 8256) * 256 + threadIdx.x; }
        union { u16 u[4]; ushort4 v; } o;
        if (f32m) {
            float4 f = ((const float4*)src)[i];
            o.u[0] = f2b(f.x); o.u[1] = f2b(f.y); o.u[2] = f2b(f.z); o.u[3] = f2b(f.w);
        } else {
            o.v = ((const ushort4*)src)[i];
        }
        ((ushort4*)dst)[i] = o.v;
        return;
    }
    // weight transpose: WT[c][r] = bf16(W[r][c])
    __shared__ alignas(16) u16 tile[64 * 65];
    int t = bid - 8320;
    const void* W; u16* WT; int rows, cols, bx, by;
    if (t < 1024)      { W = Wq;  WT = WqkvT;                    rows = 2048; cols = 2048; bx = t & 31;  by = t >> 5; }
    else if (t < 1536) { int l = t - 1024; W = Wkv; WT = WqkvT + (long)2048 * 2048; rows = 2048; cols = 1024; bx = l & 15; by = l >> 4; }
    else               { int l = t - 1536; W = Wo;  WT = WoT;  rows = 2048; cols = 2048; bx = l & 31;   by = l >> 5; }
    const int r0 = by * 64, c0 = bx * 64;
#pragma unroll
    for (int i = 0; i < 16; i++) {
        int c = threadIdx.x + i * 256;
        int rr = c >> 6, cc = c & 63;
        long idx = (long)(r0 + rr) * cols + c0 + cc;
        tile[rr * 65 + cc] = f32m ? f2b(((const float*)W)[idx]) : ((const u16*)W)[idx];
    }
    __syncthreads();
#pragma unroll
    for (int i = 0; i < 16; i++) {
        int c = threadIdx.x + i * 256;
        int rr = c >> 6, cc = c & 63;
        WT[(long)(c0 + rr) * rows + r0 + cc] = tile[cc * 65 + rr];
    }
}

// ---------------------------------------------------------------------------
// gemm_p4: R5's 4-phase single-barrier GEMM (fastest measured GEMM1 variant).
// Phase = {ds_read new frags; stage unit(s); BAR; lgkm(0); MFMA quadrant},
// no barrier after the MFMA cluster; staging split across phases; one
// vmcnt(0) per tile at P3 retiring loads issued >=1 phase earlier.
// ---------------------------------------------------------------------------
template<int BM, int BN>
__global__ __launch_bounds__(512, 2) void gemm_p4(const u16* __restrict__ A,
                                                  const u16* __restrict__ Bt,
                                                  void* __restrict__ C,
                                                  int N, int Kd,
                                                  const u16* __restrict__ xprobe) {
    constexpr int MF  = BM / 32;
    constexpr int NF  = BN / 64;
    constexpr int MF0 = MF / 2, MF1 = MF - MF0;
    constexpr int NF0 = (NF + 1) / 2, NF1 = NF - NF0;
    constexpr int NAU = BM / 64;
    constexpr int NBU = BN / 64;
    constexpr int NAL = NAU / 2;
    constexpr int NBL = NBU / 2;

    __shared__ alignas(16) u16 As[2][BM * 64];
    __shared__ alignas(16) u16 Bs[2][BN * 64];

    const bool f32m = (xprobe != nullptr) && wave_is_f32(xprobe);
    const int tid = threadIdx.x;
    const int w = tid >> 6, lane = tid & 63;
    const int wm = w >> 2, wn = w & 3;
    const int l16 = lane & 15, quad = lane >> 4;
    const long arow0 = (long)blockIdx.y * BM;
    const long brow0 = (long)blockIdx.x * BN;
    const int NT = Kd >> 6;

    const int srow = tid >> 3, scp = tid & 7;
    const long gst = (long)srow * Kd + ((scp ^ (srow & 7)) << 3);
    const int cst = tid << 3;

    const u16* Ab = A + arow0 * Kd;
    const u16* Bb = Bt + brow0 * Kd;

    auto stageA = [&](int buf, int t, int u0, int u1) {
#pragma unroll
        for (int u = 0; u < NAU; u++)
            if (u >= u0 && u < u1)
                async16(Ab + (long)u * 64 * Kd + t * 64 + gst, &As[buf][u * 4096 + cst]);
    };
    auto stageB = [&](int buf, int t, int u0, int u1) {
#pragma unroll
        for (int u = 0; u < NBU; u++)
            if (u >= u0 && u < u1)
                async16(Bb + (long)u * 64 * Kd + t * 64 + gst, &Bs[buf][u * 4096 + cst]);
    };

    const int R0a = wm * (BM / 2) + l16, sA = R0a & 7;
    const int R0b = wn * (BN / 4) + l16, sB = R0b & 7;
    int aoff[2], boff[2];
    aoff[0] = R0a * 64 + ((quad ^ sA) << 3);
    aoff[1] = R0a * 64 + (((4 + quad) ^ sA) << 3);
    boff[0] = R0b * 64 + ((quad ^ sB) << 3);
    boff[1] = R0b * 64 + (((4 + quad) ^ sB) << 3);

    f32x4 acc[MF][NF];
#pragma unroll
    for (int i = 0; i < MF; i++)
#pragma unroll
        for (int j = 0; j < NF; j++) acc[i][j] = {0.f, 0.f, 0.f, 0.f};

    stageB(0, 0, 0, NBU);
    stageA(0, 0, 0, NAU);
    stageB(1, 1, 0, NBL);
    waitvm<NBL>();
    __builtin_amdgcn_s_barrier();

#pragma unroll 1
    for (int t = 0; t < NT; ++t) {
        const int cur = t & 1, nxt = cur ^ 1;
        const u16* pA = &As[cur][0];
        const u16* pB = &Bs[cur][0];
        bf16x8 afLo[MF0][2], afHi[MF1][2], bfA[NF0][2], bfB[NF1][2];

        // ---- P0: read afLo+bfA; stage B-upper(t+1); BAR; q0 ----
#pragma unroll
        for (int ks = 0; ks < 2; ks++) {
#pragma unroll
            for (int mt = 0; mt < MF0; mt++)
                afLo[mt][ks] = *(const bf16x8*)&pA[aoff[ks] + mt * 1024];
#pragma unroll
            for (int nt = 0; nt < NF0; nt++)
                bfA[nt][ks] = *(const bf16x8*)&pB[boff[ks] + nt * 1024];
        }
        if (t + 1 < NT) stageB(nxt, t + 1, NBL, NBU);
        __builtin_amdgcn_s_barrier();
        asm volatile("s_waitcnt lgkmcnt(0)" ::: "memory");
        __builtin_amdgcn_sched_barrier(0);
        __builtin_amdgcn_s_setprio(1);
#pragma unroll
        for (int ks = 0; ks < 2; ks++)
#pragma unroll
            for (int mt = 0; mt < MF0; mt++)
#pragma unroll
                for (int nt = 0; nt < NF0; nt++)
                    acc[mt][nt] = __builtin_amdgcn_mfma_f32_16x16x32_bf16(
                        afLo[mt][ks], bfA[nt][ks], acc[mt][nt], 0, 0, 0);
        __builtin_amdgcn_s_setprio(0);

        // ---- P1: read bfB; stage A-lower(t+1); BAR; q1 ----
#pragma unroll
        for (int ks = 0; ks < 2; ks++)
#pragma unroll
            for (int nt = 0; nt < NF1; nt++)
                bfB[nt][ks] = *(const bf16x8*)&pB[boff[ks] + (NF0 + nt) * 1024];
        if (t + 1 < NT) stageA(nxt, t + 1, 0, NAL);
        __builtin_amdgcn_s_barrier();
        asm volatile("s_waitcnt lgkmcnt(0)" ::: "memory");
        __builtin_amdgcn_sched_barrier(0);
        __builtin_amdgcn_s_setprio(1);
#pragma unroll
        for (int ks = 0; ks < 2; ks++)
#pragma unroll
            for (int mt = 0; mt < MF0; mt++)
#pragma unroll
                for (int nt = 0; nt < NF1; nt++)
                    acc[mt][NF0 + nt] = __builtin_amdgcn_mfma_f32_16x16x32_bf16(
                        afLo[mt][ks], bfB[nt][ks], acc[mt][NF0 + nt], 0, 0, 0);
        __builtin_amdgcn_s_setprio(0);

        // ---- P2: read afHi; stage A-upper(t+1); BAR; q2 ----
#pragma unroll
        for (int ks = 0; ks < 2; ks++)
#pragma unroll
            for (int mt = 0; mt < MF1; mt++)
                afHi[mt][ks] = *(const bf16x8*)&pA[aoff[ks] + (MF0 + mt) * 1024];
        if (t + 1 < NT) stageA(nxt, t + 1, NAL, NAU);
        __builtin_amdgcn_s_barrier();
        asm volatile("s_waitcnt lgkmcnt(0)" ::: "memory");
        __builtin_amdgcn_sched_barrier(0);
        __builtin_amdgcn_s_setprio(1);
#pragma unroll
        for (int ks = 0; ks < 2; ks++)
#pragma unroll
            for (int mt = 0; mt < MF1; mt++)
#pragma unroll
                for (int nt = 0; nt < NF1; nt++)
                    acc[MF0 + mt][NF0 + nt] = __builtin_amdgcn_mfma_f32_16x16x32_bf16(
                        afHi[mt][ks], bfB[nt][ks], acc[MF0 + mt][NF0 + nt], 0, 0, 0);
        __builtin_amdgcn_s_setprio(0);

        // ---- P3: vmcnt(0); BAR; stage B-lower(t+2)->cur; q3 ----
        if (t + 1 < NT) {
            asm volatile("s_waitcnt vmcnt(0)" ::: "memory");
            __builtin_amdgcn_s_barrier();
            if (t + 2 < NT) stageB(cur, t + 2, 0, NBL);
        }
        __builtin_amdgcn_sched_barrier(0);
        __builtin_amdgcn_s_setprio(1);
#pragma unroll
        for (int ks = 0; ks < 2; ks++)
#pragma unroll
            for (int mt = 0; mt < MF1; mt++)
#pragma unroll
                for (int nt = 0; nt < NF0; nt++)
                    acc[MF0 + mt][nt] = __builtin_amdgcn_mfma_f32_16x16x32_bf16(
                        afHi[mt][ks], bfA[nt][ks], acc[MF0 + mt][nt], 0, 0, 0);
        __builtin_amdgcn_s_setprio(0);
    }

#pragma unroll
    for (int mt = 0; mt < MF; mt++) {
#pragma unroll
        for (int nt = 0; nt < NF; nt++) {
            long col = brow0 + wn * (BN / 4) + nt * 16 + l16;
#pragma unroll
            for (int r = 0; r < 4; r++) {
                long row = arow0 + wm * (BM / 2) + mt * 16 + quad * 4 + r;
                if (f32m) ((float*)C)[row * N + col] = acc[mt][nt][r];
                else      ((u16*)C)[row * N + col] = f2b(acc[mt][nt][r]);
            }
        }
    }
}

// ---------------------------------------------------------------------------
// gemm_p2: R4's 2-phase GEMM with two-tile-deep staging and counted vmcnt
// (the config from the best-total round; its per-dispatch time is the
// measurement target this round).
//  Phase A: ds_read afLo+bfA+bfB; lgkm(0); MFMA q0,q1
//  Phase B: ds_read afHi; BAR; stage B(t+2)->cur; lgkm(0); MFMA q2,q3;
//           vmcnt(NBU); BAR; stage A(t+2)->cur
// ---------------------------------------------------------------------------
template<int BM, int BN>
__global__ __launch_bounds__(512, 2) void gemm_p2(const u16* __restrict__ A,
                                                  const u16* __restrict__ Bt,
                                                  void* __restrict__ C,
                                                  int N, int Kd,
                                                  const u16* __restrict__ xprobe) {
    constexpr int MF  = BM / 32;
    constexpr int NF  = BN / 64;
    constexpr int MF0 = MF / 2, MF1 = MF - MF0;
    constexpr int NF0 = (NF + 1) / 2, NF1 = NF - NF0;
    constexpr int NAU = BM / 64;
    constexpr int NBU = BN / 64;

    __shared__ alignas(16) u16 As[2][BM * 64];
    __shared__ alignas(16) u16 Bs[2][BN * 64];

    const bool f32m = (xprobe != nullptr) && wave_is_f32(xprobe);
    const int tid = threadIdx.x;
    const int w = tid >> 6, lane = tid & 63;
    const int wm = w >> 2, wn = w & 3;
    const int l16 = lane & 15, quad = lane >> 4;
    const long arow0 = (long)blockIdx.y * BM;
    const long brow0 = (long)blockIdx.x * BN;
    const int NT = Kd >> 6;

    const int srow = tid >> 3, scp = tid & 7;
    const long gst = (long)srow * Kd + ((scp ^ (srow & 7)) << 3);
    const int cst = tid << 3;

    const u16* Ab = A + arow0 * Kd;
    const u16* Bb = Bt + brow0 * Kd;

    auto stageA = [&](int buf, int t) {
#pragma unroll
        for (int u = 0; u < NAU; u++)
            async16(Ab + (long)u * 64 * Kd + t * 64 + gst, &As[buf][u * 4096 + cst]);
    };
    auto stageB = [&](int buf, int t) {
#pragma unroll
        for (int u = 0; u < NBU; u++)
            async16(Bb + (long)u * 64 * Kd + t * 64 + gst, &Bs[buf][u * 4096 + cst]);
    };

    const int R0a = wm * (BM / 2) + l16, sA = R0a & 7;
    const int R0b = wn * (BN / 4) + l16, sB = R0b & 7;
    int aoff[2], boff[2];
    aoff[0] = R0a * 64 + ((quad ^ sA) << 3);
    aoff[1] = R0a * 64 + (((4 + quad) ^ sA) << 3);
    boff[0] = R0b * 64 + ((quad ^ sB) << 3);
    boff[1] = R0b * 64 + (((4 + quad) ^ sB) << 3);

    f32x4 acc[MF][NF];
#pragma unroll
    for (int i = 0; i < MF; i++)
#pragma unroll
        for (int j = 0; j < NF; j++) acc[i][j] = {0.f, 0.f, 0.f, 0.f};

    stageB(0, 0); stageA(0, 0); stageB(1, 1); stageA(1, 1);
    waitvm<NAU + NBU>();
    __builtin_amdgcn_s_barrier();

#pragma unroll 1
    for (int t = 0; t < NT; ++t) {
        const int cur = t & 1;
        const u16* pA = &As[cur][0];
        const u16* pB = &Bs[cur][0];
        bf16x8 afLo[MF0][2], afHi[MF1][2], bfA[NF0][2], bfB[NF1][2];

        // ---- Phase A: read Lo set; lgkm(0); MFMA q0+q1 ----
#pragma unroll
        for (int ks = 0; ks < 2; ks++) {
#pragma unroll
            for (int mt = 0; mt < MF0; mt++)
                afLo[mt][ks] = *(const bf16x8*)&pA[aoff[ks] + mt * 1024];
#pragma unroll
            for (int nt = 0; nt < NF0; nt++)
                bfA[nt][ks] = *(const bf16x8*)&pB[boff[ks] + nt * 1024];
#pragma unroll
            for (int nt = 0; nt < NF1; nt++)
                bfB[nt][ks] = *(const bf16x8*)&pB[boff[ks] + (NF0 + nt) * 1024];
        }
        asm volatile("s_waitcnt lgkmcnt(0)" ::: "memory");
        __builtin_amdgcn_sched_barrier(0);
        __builtin_amdgcn_s_setprio(1);
#pragma unroll
        for (int ks = 0; ks < 2; ks++)
#pragma unroll
            for (int mt = 0; mt < MF0; mt++) {
#pragma unroll
                for (int nt = 0; nt < NF0; nt++)
                    acc[mt][nt] = __builtin_amdgcn_mfma_f32_16x16x32_bf16(
                        afLo[mt][ks], bfA[nt][ks], acc[mt][nt], 0, 0, 0);
#pragma unroll
                for (int nt = 0; nt < NF1; nt++)
                    acc[mt][NF0 + nt] = __builtin_amdgcn_mfma_f32_16x16x32_bf16(
                        afLo[mt][ks], bfB[nt][ks], acc[mt][NF0 + nt], 0, 0, 0);
            }
        __builtin_amdgcn_s_setprio(0);

        // ---- Phase B: read afHi; BAR; stage B(t+2); lgkm(0); MFMA q2+q3 ----
#pragma unroll
        for (int ks = 0; ks < 2; ks++)
#pragma unroll
            for (int mt = 0; mt < MF1; mt++)
                afHi[mt][ks] = *(const bf16x8*)&pA[aoff[ks] + (MF0 + mt) * 1024];
        __builtin_amdgcn_s_barrier();
        if (t + 2 < NT) stageB(cur, t + 2);
        asm volatile("s_waitcnt lgkmcnt(0)" ::: "memory");
        __builtin_amdgcn_sched_barrier(0);
        __builtin_amdgcn_s_setprio(1);
#pragma unroll
        for (int ks = 0; ks < 2; ks++)
#pragma unroll
            for (int mt = 0; mt < MF1; mt++) {
#pragma unroll
                for (int nt = 0; nt < NF1; nt++)
                    acc[MF0 + mt][NF0 + nt] = __builtin_amdgcn_mfma_f32_16x16x32_bf16(
                        afHi[mt][ks], bfB[nt][ks], acc[MF0 + mt][NF0 + nt], 0, 0, 0);
#pragma unroll
                for (int nt = 0; nt < NF0; nt++)
                    acc[MF0 + mt][nt] = __builtin_amdgcn_mfma_f32_16x16x32_bf16(
                        afHi[mt][ks], bfA[nt][ks], acc[MF0 + mt][nt], 0, 0, 0);
            }
        __builtin_amdgcn_s_setprio(0);

        // ---- tile boundary: retire tile t+1's staging; stage A(t+2) ----
        if (t + 1 < NT) {
            if (t + 2 < NT) waitvm<NBU>();
            else            waitvm<0>();
            __builtin_amdgcn_s_barrier();
            if (t + 2 < NT) stageA(cur, t + 2);
        }
    }

#pragma unroll
    for (int mt = 0; mt < MF; mt++) {
#pragma unroll
        for (int nt = 0; nt < NF; nt++) {
            long col = brow0 + wn * (BN / 4) + nt * 16 + l16;
#pragma unroll
            for (int r = 0; r < 4; r++) {
                long row = arow0 + wm * (BM / 2) + mt * 16 + quad * 4 + r;
                if (f32m) ((float*)C)[row * N + col] = acc[mt][nt][r];
                else      ((u16*)C)[row * N + col] = f2b(acc[mt][nt][r]);
            }
        }
    }
}

// ---------------------------------------------------------------------------
// RoPE(Q), RoPE(K), V-transpose in one dispatch, split by block ranges.
// V is now a 64x64 LDS tile transpose (coalesced ushort4 both sides) --
// replaces the old per-lane scalar u16 reads at 6KB stride.
// Blocks: [0,16384) Q | [16384,20480) K | [20480,20992) V.
// ---------------------------------------------------------------------------
__global__ __launch_bounds__(256) void prep_k(const u16* __restrict__ QKVraw,
                                              const u16* __restrict__ cs,
                                              const u16* __restrict__ sn,
                                              u16* __restrict__ Qr,
                                              u16* __restrict__ Kr,
                                              u16* __restrict__ Vt) {
    __shared__ alignas(16) u16 tile[64 * 68];
    int bid = blockIdx.x;
    if (bid < 16384) {                       // RoPE Q -> (B,H,T,HD)
        int idx = bid * 256 + threadIdx.x;
        int d = idx & 63;
        int t = (idx >> 6) & (TT - 1);
        int bh = idx >> 16;
        long src = ((long)((bh >> 4) * TT + t)) * 3072 + (bh & 15) * HDIM;
        float u1 = b2f(QKVraw[src + d]), u2 = b2f(QKVraw[src + d + 64]);
        float c = b2f(cs[t * 64 + d]), s = b2f(sn[t * 64 + d]);
        long dst = ((long)bh * TT + t) * HDIM;
        Qr[dst + d] = f2b(u1 * c - u2 * s);
        Qr[dst + d + 64] = f2b(u1 * s + u2 * c);
    } else if (bid < 20480) {                // RoPE K -> (B,KVH,T,HD)
        int idx = (bid - 16384) * 256 + threadIdx.x;
        int d = idx & 63;
        int t = (idx >> 6) & (TT - 1);
        int bk = idx >> 16;
        long src = ((long)((bk >> 2) * TT + t)) * 3072 + 2048 + (bk & 3) * HDIM;
        float u1 = b2f(QKVraw[src + d]), u2 = b2f(QKVraw[src + d + 64]);
        float c = b2f(cs[t * 64 + d]), s = b2f(sn[t * 64 + d]);
        long dst = ((long)bk * TT + t) * HDIM;
        Kr[dst + d] = f2b(u1 * c - u2 * s);
        Kr[dst + d + 64] = f2b(u1 * s + u2 * c);
    } else {                                 // V -> (B,KVH,HD,T) via LDS transpose
        int vb = bid - 20480;                // [0,512)
        int bk = vb >> 5;                    // (b*NKV + kvh)
        int dt = (vb >> 4) & 1;              // d-tile (0..1)
        int tt = vb & 15;                    // t-tile (0..15)
        const int d0 = dt * 64, t0 = tt * 64;
        const long srcb = ((long)(bk >> 2) * TT) * 3072 + 2560 + (bk & 3) * HDIM;
#pragma unroll
        for (int i = 0; i < 4; i++) {
            int lin = i * 256 + threadIdx.x;
            int r = lin >> 4, c4 = (lin & 15) * 4;   // r = t-row, c4 = d-col
            *(ushort4*)&tile[r * 68 + c4] =
                *(const ushort4*)&QKVraw[srcb + (long)(t0 + r) * 3072 + d0 + c4];
        }
        __syncthreads();
        const long dstb = ((long)bk * 128 + d0) * 1024 + t0;
#pragma unroll
        for (int i = 0; i < 4; i++) {
            int lin = i * 256 + threadIdx.x;
            int dr = lin >> 4, c4 = (lin & 15) * 4;  // dr = d-row, c4 = t-col
            ushort4 v;
            v.x = tile[(c4 + 0) * 68 + dr];
            v.y = tile[(c4 + 1) * 68 + dr];
            v.z = tile[(c4 + 2) * 68 + dr];
            v.w = tile[(c4 + 3) * 68 + dr];
            *(ushort4*)&Vt[dstb + (long)dr * 1024 + c4] = v;
        }
    }
}

// ---------------------------------------------------------------------------
// Flash attention v5: balanced persistent pairs + double-buffered K/V with
// fine-grained vmcnt (loads stay in flight across compute; vmcnt(0) never
// runs inside the K-loop). 1024 items (bh, qt) sorted heavy-first; block b
// does items {b, 1023-b} => exactly 17 tile-iterations per block; grid 512
// = 2 blocks/CU resident (LDS 75KB). Compute per tile identical to R4/R6
// (verified): S^T = K·Q^T, in-lane online softmax, Ps LDS hop, O^T = V^T·P^T.
// ---------------------------------------------------------------------------
__global__ __launch_bounds__(256) void attn_kernel(const u16* __restrict__ Q,
                                                   const u16* __restrict__ Kr,
                                                   const u16* __restrict__ Vt,
                                                   u16* __restrict__ O) {
    __shared__ alignas(16) u16 Ks[2][64 * 128];   // [t][d], chunk ^= row&7 (bit3 kept)
    __shared__ alignas(16) u16 Vts[2][128 * 64];  // [d][t], chunk ^= row&7
    __shared__ alignas(16) u16 Ps[64 * 88];       // [q][k], per-wave rows only

    const int tid = threadIdx.x, w = tid >> 6, lane = tid & 63;
    const int l16 = lane & 15, quad = lane >> 4;
    const float scale2 = 0.08838834764831845f * 1.4426950408889634f; // 1/sqrt(128)*log2e

#pragma unroll 1
    for (int it = 0; it < 2; it++) {
        const int j = it ? (1023 - (int)blockIdx.x) : (int)blockIdx.x;
        const int qt = 15 - (j >> 6);        // heavy first for it==0
        const int bh = j & 63;
        const int b = bh >> 4, h = bh & 15;
        const int kvh = h >> 2;
        const long qrow0 = (long)bh * TT + qt * 64;
        const long krow0 = (long)(b * NKV + kvh) * TT;
        const long vbase = ((long)(b * NKV + kvh) * HDIM) * TT;

        __syncthreads();  // prior item's LDS reads done; full drain

        // ---- stage this wave's 16 Q rows through Ks[0] (own slots only) ----
#pragma unroll
        for (int i = 0; i < 4; i++) {
            int slot0 = (w * 4 + i) * 64;
            int slot = slot0 + lane;
            int row = slot >> 4, cp = slot & 15;
            int cg = (cp & 8) | ((cp ^ row) & 7);
            async16(Q + (qrow0 + row) * HDIM + cg * 8, &Ks[0][slot0 * 8]);
        }
        asm volatile("s_waitcnt vmcnt(0)" ::: "memory");
        bf16x8 qf[4];
        {
            const int Rq = w * 16 + l16;
#pragma unroll
            for (int ds = 0; ds < 4; ds++) {
                int c = ds * 4 + quad;
                qf[ds] = *(const bf16x8*)&Ks[0][Rq * 128 + ((c & 8) | ((c ^ Rq) & 7)) * 8];
            }
        }
        asm volatile("s_waitcnt lgkmcnt(0)" ::: "memory");  // frags in regs

        // ---- prologue staging: tile0 -> buf0 (overwrites Q, own slots), tile1 -> buf1
#pragma unroll
        for (int i = 0; i < 4; i++) {
            int slot0 = (w * 4 + i) * 64;
            int slot = slot0 + lane;
            int row = slot >> 4, cp = slot & 15;
            int cg = (cp & 8) | ((cp ^ row) & 7);
            async16(Kr + (krow0 + row) * HDIM + cg * 8, &Ks[0][slot0 * 8]);
        }
#pragma unroll
        for (int i = 0; i < 4; i++) {
            int slot0 = (w * 4 + i) * 64;
            int slot = slot0 + lane;
            int row = slot >> 3, cp = slot & 7;
            int cg = cp ^ (row & 7);
            async16(Vt + vbase + (long)row * TT + cg * 8, &Vts[0][slot0 * 8]);
        }
        if (qt >= 1) {
#pragma unroll
            for (int i = 0; i < 4; i++) {
                int slot0 = (w * 4 + i) * 64;
                int slot = slot0 + lane;
                int row = slot >> 4, cp = slot & 15;
                int cg = (cp & 8) | ((cp ^ row) & 7);
                async16(Kr + (krow0 + 64 + row) * HDIM + cg * 8, &Ks[1][slot0 * 8]);
            }
#pragma unroll
            for (int i = 0; i < 4; i++) {
                int slot0 = (w * 4 + i) * 64;
                int slot = slot0 + lane;
                int row = slot >> 3, cp = slot & 7;
                int cg = cp ^ (row & 7);
                async16(Vt + vbase + (long)row * TT + 64 + cg * 8, &Vts[1][slot0 * 8]);
            }
            asm volatile("s_waitcnt vmcnt(8)" ::: "memory");  // tile0 done, tile1 in flight
        } else {
            asm volatile("s_waitcnt vmcnt(0)" ::: "memory");
        }
        asm volatile("s_barrier" ::: "memory");

        f32x4 o[8];
#pragma unroll
        for (int i = 0; i < 8; i++) o[i] = {0.f, 0.f, 0.f, 0.f};
        float m_i = -1.0e30f, l_i = 0.f;
        const int qg = qt * 64 + w * 16 + l16;

#pragma unroll 1
        for (int kt = 0; kt <= qt; kt++) {
            const int cur = kt & 1;
            const u16* ksb = Ks[cur];
            const u16* vsb = Vts[cur];

            // S^T[k][q] = sum_d K[k][d] * Q[q][d]
            f32x4 s[4];
#pragma unroll
            for (int nt = 0; nt < 4; nt++) s[nt] = {0.f, 0.f, 0.f, 0.f};
#pragma unroll
            for (int ds = 0; ds < 4; ds++) {
                int c = ds * 4 + quad;
#pragma unroll
                for (int nt = 0; nt < 4; nt++) {
                    int Rk = nt * 16 + l16;
                    bf16x8 ak = *(const bf16x8*)&ksb[Rk * 128 + ((c & 8) | ((c ^ Rk) & 7)) * 8];
                    s[nt] = __builtin_amdgcn_mfma_f32_16x16x32_bf16(ak, qf[ds], s[nt], 0, 0, 0);
                }
            }

            // online softmax (exp2 domain), in-lane 16 values + 2 shuffles
            float p[4][4];
            float mx = -1.0e30f;
            if (kt == qt) {
#pragma unroll
                for (int nt = 0; nt < 4; nt++)
#pragma unroll
                    for (int r = 0; r < 4; r++) {
                        int kcol = kt * 64 + nt * 16 + quad * 4 + r;
                        float v = (kcol <= qg) ? (float)s[nt][r] * scale2 : -1.0e30f;
                        p[nt][r] = v;
                        mx = fmaxf(mx, v);
                    }
            } else {
#pragma unroll
                for (int nt = 0; nt < 4; nt++)
#pragma unroll
                    for (int r = 0; r < 4; r++) {
                        float v = (float)s[nt][r] * scale2;
                        p[nt][r] = v;
                        mx = fmaxf(mx, v);
                    }
            }
            mx = fmaxf(mx, __shfl_xor(mx, 16));
            mx = fmaxf(mx, __shfl_xor(mx, 32));
            float mnew = fmaxf(m_i, mx);
            float alpha = exp2f(m_i - mnew);
            float rs = 0.f;
#pragma unroll
            for (int nt = 0; nt < 4; nt++)
#pragma unroll
                for (int r = 0; r < 4; r++) {
                    float e = exp2f(p[nt][r] - mnew);
                    p[nt][r] = e;
                    rs += e;
                }
            rs += __shfl_xor(rs, 16);
            rs += __shfl_xor(rs, 32);
            l_i = l_i * alpha + rs;

            // P -> Ps (packed u32, own-wave rows)
            u32* Psw = (u32*)Ps;
            int pb = (w * 16 + l16) * 44 + quad * 2;
#pragma unroll
            for (int nt = 0; nt < 4; nt++) {
                u32 lo = (u32)f2b(p[nt][0]) | ((u32)f2b(p[nt][1]) << 16);
                u32 hi = (u32)f2b(p[nt][2]) | ((u32)f2b(p[nt][3]) << 16);
                Psw[pb + nt * 8]     = lo;
                Psw[pb + nt * 8 + 1] = hi;
            }
            if (__ballot(mnew != m_i) != 0ULL) {
#pragma unroll
                for (int n8 = 0; n8 < 8; n8++)
#pragma unroll
                    for (int r = 0; r < 4; r++) o[n8][r] *= alpha;
            }
            m_i = mnew;

            asm volatile("s_waitcnt lgkmcnt(0)" ::: "memory");  // Ps W->R, same wave

            // O^T[d][q] += V^T[d][k] * P[q][k]
#pragma unroll
            for (int ks = 0; ks < 2; ks++) {
                bf16x8 bp = *(const bf16x8*)&Ps[(w * 16 + l16) * 88 + ks * 32 + quad * 8];
#pragma unroll
                for (int n8 = 0; n8 < 8; n8++) {
                    int Rv = n8 * 16 + l16;
                    int c = ks * 4 + quad;
                    bf16x8 av = *(const bf16x8*)&vsb[Rv * 64 + (c ^ (Rv & 7)) * 8];
                    o[n8] = __builtin_amdgcn_mfma_f32_16x16x32_bf16(av, bp, o[n8], 0, 0, 0);
                }
            }

            if (kt == qt) break;

            // pipeline maintenance: reads of buf[cur] done -> refill it with kt+2
            asm volatile("s_waitcnt lgkmcnt(0)" ::: "memory");  // own ds_reads complete
            asm volatile("s_barrier" ::: "memory");             // all waves done with buf[cur]
            if (kt + 2 <= qt) {
                const int nk = kt + 2;
#pragma unroll
                for (int i = 0; i < 4; i++) {
                    int slot0 = (w * 4 + i) * 64;
                    int slot = slot0 + lane;
                    int row = slot >> 4, cp = slot & 15;
                    int cg = (cp & 8) | ((cp ^ row) & 7);
                    async16(Kr + (krow0 + nk * 64 + row) * HDIM + cg * 8, &Ks[cur][slot0 * 8]);
                }
#pragma unroll
                for (int i = 0; i < 4; i++) {
                    int slot0 = (w * 4 + i) * 64;
                    int slot = slot0 + lane;
                    int row = slot >> 3, cp = slot & 7;
                    int cg = cp ^ (row & 7);
                    async16(Vt + vbase + (long)row * TT + nk * 64 + cg * 8, &Vts[cur][slot0 * 8]);
                }
                asm volatile("s_waitcnt vmcnt(8)" ::: "memory");  // (kt+1)'s loads done
            } else {
                asm volatile("s_waitcnt vmcnt(0)" ::: "memory");
            }
            asm volatile("s_barrier" ::: "memory");  // buf[1-cur] ready across waves
        }

        // epilogue: normalize, pack, store this item's 64 q-rows
        float inv = 1.0f / l_i;
        long obase = ((long)(b * TT + qg)) * CDIM + h * HDIM;
#pragma unroll
        for (int n8 = 0; n8 < 8; n8++) {
            ushort4 st;
            st.x = f2b(o[n8][0] * inv);
            st.y = f2b(o[n8][1] * inv);
            st.z = f2b(o[n8][2] * inv);
            st.w = f2b(o[n8][3] * inv);
            *(ushort4*)&O[obase + n8 * 16 + quad * 4] = st;
        }
    }
}

// ---------------------------------------------------------------------------
extern "C" void kernel_launch(void* const* d_in, const int* in_sizes, int n_in,
                              void* d_out, int out_size, void* d_ws, size_t ws_size,
                              hipStream_t stream) {
    const void* x   = d_in[0];
    const void* Wq  = d_in[1];
    const void* Wkv = d_in[2];
    const void* Wo  = d_in[3];
    const void* cs  = d_in[4];
    const void* sn  = d_in[5];

    char* ws = (char*)d_ws;
    const size_t NEED = 105119748;
    if (ws_size < NEED) return;

    u16* WqkvT = (u16*)(ws + 0);          // 3072x2048 (WqT ++ WkvT)
    u16* WoT   = (u16*)(ws + 12582912);   // 2048x2048
    u16* QKVraw= (u16*)(ws + 20971520);   // 4096x3072
    u16* Qr    = (u16*)(ws + 46137344);   // (B,H,T,HD)
    u16* Kr    = (u16*)(ws + 62914560);   // (B,KVH,T,HD)
    u16* Vt    = (u16*)(ws + 67108864);   // (B,KVH,HD,T)
    u16* ATT   = (u16*)(ws + 71303168);   // 4096x2048
    u16* xb    = (u16*)(ws + 88080384);   // 4096x2048 bf16 x
    u16* csb   = (u16*)(ws + 104857600);  // 1024x64
    u16* snb   = (u16*)(ws + 104988672);  // 1024x64

    pre_k<<<10880, 256, 0, stream>>>(x, Wq, Wkv, Wo, xb, csb, snb, WqkvT, WoT, cs, sn);

    // GEMM1: 4096x3072x2048, tile 256x192, 4-phase -> grid 16x16 = 256 WGs
    gemm_p4<256, 192><<<dim3(16, 16), 512, 0, stream>>>(xb, WqkvT, QKVraw, 3072, 2048, nullptr);

    prep_k<<<20992, 256, 0, stream>>>(QKVraw, csb, snb, Qr, Kr, Vt);

    attn_kernel<<<512, 256, 0, stream>>>(Qr, Kr, Vt, ATT);

    // GEMM2: 4096x2048x2048, tile 128x256, 2-phase -> grid 8x32 = 256 WGs
    gemm_p2<128, 256><<<dim3(8, 32), 512, 0, stream>>>(ATT, WoT, d_out, 2048, 2048, (const u16*)x);
}

// Round 9
// 287.210 us; speedup vs baseline: 1.1483x; 1.0427x over previous
//
#include <hip/hip_runtime.h>

typedef unsigned short u16;
typedef unsigned int u32;
typedef __bf16 bf16x8 __attribute__((ext_vector_type(8)));
typedef float f32x4 __attribute__((ext_vector_type(4)));

#define BB   4
#define TT   1024
#define CDIM 2048
#define NH   16
#define NKV  4
#define HDIM 128

__device__ __forceinline__ float b2f(u16 u) {
    union { u32 i; float f; } x; x.i = ((u32)u) << 16; return x.f;
}
__device__ __forceinline__ u16 f2b(float f) {
    union { float f; u32 i; } x; x.f = f;
    u32 r = (x.i + 0x7fffu + ((x.i >> 16) & 1u)) >> 16;
    return (u16)r;
}
__device__ __forceinline__ void async16(const void* g, void* l) {
    __builtin_amdgcn_global_load_lds((const __attribute__((address_space(1))) void*)g,
                                     (__attribute__((address_space(3))) void*)l, 16, 0, 0);
}
template<int N> __device__ __forceinline__ void waitvm() {
    static_assert(N >= 0 && N <= 8, "unsupported vmcnt");
    if constexpr (N == 0)      asm volatile("s_waitcnt vmcnt(0)" ::: "memory");
    else if constexpr (N == 1) asm volatile("s_waitcnt vmcnt(1)" ::: "memory");
    else if constexpr (N == 2) asm volatile("s_waitcnt vmcnt(2)" ::: "memory");
    else if constexpr (N == 3) asm volatile("s_waitcnt vmcnt(3)" ::: "memory");
    else if constexpr (N == 4) asm volatile("s_waitcnt vmcnt(4)" ::: "memory");
    else if constexpr (N == 5) asm volatile("s_waitcnt vmcnt(5)" ::: "memory");
    else if constexpr (N == 6) asm volatile("s_waitcnt vmcnt(6)" ::: "memory");
    else if constexpr (N == 7) asm volatile("s_waitcnt vmcnt(7)" ::: "memory");
    else                       asm volatile("s_waitcnt vmcnt(8)" ::: "memory");
}

// Inline dtype probe: every wave samples the same 64 even u16s of x (low
// mantissa halves if fp32 -> uniform-random exponents -> ~72% implausible;
// real bf16 N(0,1) -> ~0%). Ballot => identical wave-uniform verdict everywhere.
__device__ __forceinline__ bool wave_is_f32(const u16* xp) {
    u16 v = xp[(threadIdx.x & 63) * 2];
    int e = (v >> 7) & 0xFF;
    bool bad = (v != 0) && (e < 90 || e > 160);
    return __popcll(__ballot(bad)) > 16;
}

// ---------------------------------------------------------------------------
// Fused pre-pass: convert x, cos, sin to bf16 + all three weight transposes.
// Block ranges: [0,8192) x | [8192,8256) cos | [8256,8320) sin | [8320,10880) W.
// ---------------------------------------------------------------------------
__global__ __launch_bounds__(256) void pre_k(const void* __restrict__ x,
                                             const void* __restrict__ Wq,
                                             const void* __restrict__ Wkv,
                                             const void* __restrict__ Wo,
                                             u16* __restrict__ xb,
                                             u16* __restrict__ csb,
                                             u16* __restrict__ snb,
                                             u16* __restrict__ WqkvT,
                                             u16* __restrict__ WoT,
                                             const void* __restrict__ cs,
                                             const void* __restrict__ sn) {
    const bool f32m = wave_is_f32((const u16*)x);
    int bid = blockIdx.x;
    if (bid < 8320) {                        // element-wise conversions
        const void* src; u16* dst; int i;
        if (bid < 8192)      { src = x;  dst = xb;  i = bid * 256 + threadIdx.x; }
        else if (bid < 8256) { src = cs; dst = csb; i = (bid - 8192) * 256 + threadIdx.x; }
        else                 { src = sn; dst = snb; i = (bid - 8256) * 256 + threadIdx.x; }
        union { u16 u[4]; ushort4 v; } o;
        if (f32m) {
            float4 f = ((const float4*)src)[i];
            o.u[0] = f2b(f.x); o.u[1] = f2b(f.y); o.u[2] = f2b(f.z); o.u[3] = f2b(f.w);
        } else {
            o.v = ((const ushort4*)src)[i];
        }
        ((ushort4*)dst)[i] = o.v;
        return;
    }
    // weight transpose: WT[c][r] = bf16(W[r][c])
    __shared__ alignas(16) u16 tile[64 * 65];
    int t = bid - 8320;
    const void* W; u16* WT; int rows, cols, bx, by;
    if (t < 1024)      { W = Wq;  WT = WqkvT;                    rows = 2048; cols = 2048; bx = t & 31;  by = t >> 5; }
    else if (t < 1536) { int l = t - 1024; W = Wkv; WT = WqkvT + (long)2048 * 2048; rows = 2048; cols = 1024; bx = l & 15; by = l >> 4; }
    else               { int l = t - 1536; W = Wo;  WT = WoT;  rows = 2048; cols = 2048; bx = l & 31;   by = l >> 5; }
    const int r0 = by * 64, c0 = bx * 64;
#pragma unroll
    for (int i = 0; i < 16; i++) {
        int c = threadIdx.x + i * 256;
        int rr = c >> 6, cc = c & 63;
        long idx = (long)(r0 + rr) * cols + c0 + cc;
        tile[rr * 65 + cc] = f32m ? f2b(((const float*)W)[idx]) : ((const u16*)W)[idx];
    }
    __syncthreads();
#pragma unroll
    for (int i = 0; i < 16; i++) {
        int c = threadIdx.x + i * 256;
        int rr = c >> 6, cc = c & 63;
        WT[(long)(c0 + rr) * rows + r0 + cc] = tile[cc * 65 + rr];
    }
}

// ---------------------------------------------------------------------------
// gemm_p4: 4-phase single-barrier GEMM (R5/R8 schedule, unchanged) at tiles
// small enough for TWO blocks per CU: <128,192> -> LDS 80 KiB, 2 x 80 KiB =
// exactly the 160 KiB pool. The 2nd resident block's compute hides the 1st's
// barrier/waitcnt stalls (the ~5000cyc/tile plateau was latency, not BW:
// MfmaUtil 30 + VALUBusy 18 -> >50% idle). __launch_bounds__(512,4) caps
// VGPR+AGPR at 128/wave (acc is only 48 AGPR at MF=4,NF=3).
// ---------------------------------------------------------------------------
template<int BM, int BN>
__global__ __launch_bounds__(512, 4) void gemm_p4(const u16* __restrict__ A,
                                                  const u16* __restrict__ Bt,
                                                  void* __restrict__ C,
                                                  int N, int Kd,
                                                  const u16* __restrict__ xprobe) {
    constexpr int MF  = BM / 32;
    constexpr int NF  = BN / 64;
    constexpr int MF0 = MF / 2, MF1 = MF - MF0;
    constexpr int NF0 = (NF + 1) / 2, NF1 = NF - NF0;
    constexpr int NAU = BM / 64;
    constexpr int NBU = BN / 64;
    constexpr int NAL = NAU / 2;
    constexpr int NBL = NBU / 2;

    __shared__ alignas(16) u16 As[2][BM * 64];
    __shared__ alignas(16) u16 Bs[2][BN * 64];

    const bool f32m = (xprobe != nullptr) && wave_is_f32(xprobe);
    const int tid = threadIdx.x;
    const int w = tid >> 6, lane = tid & 63;
    const int wm = w >> 2, wn = w & 3;
    const int l16 = lane & 15, quad = lane >> 4;
    const long arow0 = (long)blockIdx.y * BM;
    const long brow0 = (long)blockIdx.x * BN;
    const int NT = Kd >> 6;

    const int srow = tid >> 3, scp = tid & 7;
    const long gst = (long)srow * Kd + ((scp ^ (srow & 7)) << 3);
    const int cst = tid << 3;

    const u16* Ab = A + arow0 * Kd;
    const u16* Bb = Bt + brow0 * Kd;

    auto stageA = [&](int buf, int t, int u0, int u1) {
#pragma unroll
        for (int u = 0; u < NAU; u++)
            if (u >= u0 && u < u1)
                async16(Ab + (long)u * 64 * Kd + t * 64 + gst, &As[buf][u * 4096 + cst]);
    };
    auto stageB = [&](int buf, int t, int u0, int u1) {
#pragma unroll
        for (int u = 0; u < NBU; u++)
            if (u >= u0 && u < u1)
                async16(Bb + (long)u * 64 * Kd + t * 64 + gst, &Bs[buf][u * 4096 + cst]);
    };

    const int R0a = wm * (BM / 2) + l16, sA = R0a & 7;
    const int R0b = wn * (BN / 4) + l16, sB = R0b & 7;
    int aoff[2], boff[2];
    aoff[0] = R0a * 64 + ((quad ^ sA) << 3);
    aoff[1] = R0a * 64 + (((4 + quad) ^ sA) << 3);
    boff[0] = R0b * 64 + ((quad ^ sB) << 3);
    boff[1] = R0b * 64 + (((4 + quad) ^ sB) << 3);

    f32x4 acc[MF][NF];
#pragma unroll
    for (int i = 0; i < MF; i++)
#pragma unroll
        for (int j = 0; j < NF; j++) acc[i][j] = {0.f, 0.f, 0.f, 0.f};

    stageB(0, 0, 0, NBU);
    stageA(0, 0, 0, NAU);
    stageB(1, 1, 0, NBL);
    waitvm<NBL>();
    __builtin_amdgcn_s_barrier();

#pragma unroll 1
    for (int t = 0; t < NT; ++t) {
        const int cur = t & 1, nxt = cur ^ 1;
        const u16* pA = &As[cur][0];
        const u16* pB = &Bs[cur][0];
        bf16x8 afLo[MF0][2], afHi[MF1][2], bfA[NF0][2], bfB[NF1][2];

        // ---- P0: read afLo+bfA; stage B-upper(t+1); BAR; q0 ----
#pragma unroll
        for (int ks = 0; ks < 2; ks++) {
#pragma unroll
            for (int mt = 0; mt < MF0; mt++)
                afLo[mt][ks] = *(const bf16x8*)&pA[aoff[ks] + mt * 1024];
#pragma unroll
            for (int nt = 0; nt < NF0; nt++)
                bfA[nt][ks] = *(const bf16x8*)&pB[boff[ks] + nt * 1024];
        }
        if (t + 1 < NT) stageB(nxt, t + 1, NBL, NBU);
        __builtin_amdgcn_s_barrier();
        asm volatile("s_waitcnt lgkmcnt(0)" ::: "memory");
        __builtin_amdgcn_sched_barrier(0);
        __builtin_amdgcn_s_setprio(1);
#pragma unroll
        for (int ks = 0; ks < 2; ks++)
#pragma unroll
            for (int mt = 0; mt < MF0; mt++)
#pragma unroll
                for (int nt = 0; nt < NF0; nt++)
                    acc[mt][nt] = __builtin_amdgcn_mfma_f32_16x16x32_bf16(
                        afLo[mt][ks], bfA[nt][ks], acc[mt][nt], 0, 0, 0);
        __builtin_amdgcn_s_setprio(0);

        // ---- P1: read bfB; stage A-lower(t+1); BAR; q1 ----
#pragma unroll
        for (int ks = 0; ks < 2; ks++)
#pragma unroll
            for (int nt = 0; nt < NF1; nt++)
                bfB[nt][ks] = *(const bf16x8*)&pB[boff[ks] + (NF0 + nt) * 1024];
        if (t + 1 < NT) stageA(nxt, t + 1, 0, NAL);
        __builtin_amdgcn_s_barrier();
        asm volatile("s_waitcnt lgkmcnt(0)" ::: "memory");
        __builtin_amdgcn_sched_barrier(0);
        __builtin_amdgcn_s_setprio(1);
#pragma unroll
        for (int ks = 0; ks < 2; ks++)
#pragma unroll
            for (int mt = 0; mt < MF0; mt++)
#pragma unroll
                for (int nt = 0; nt < NF1; nt++)
                    acc[mt][NF0 + nt] = __builtin_amdgcn_mfma_f32_16x16x32_bf16(
                        afLo[mt][ks], bfB[nt][ks], acc[mt][NF0 + nt], 0, 0, 0);
        __builtin_amdgcn_s_setprio(0);

        // ---- P2: read afHi; stage A-upper(t+1); BAR; q2 ----
#pragma unroll
        for (int ks = 0; ks < 2; ks++)
#pragma unroll
            for (int mt = 0; mt < MF1; mt++)
                afHi[mt][ks] = *(const bf16x8*)&pA[aoff[ks] + (MF0 + mt) * 1024];
        if (t + 1 < NT) stageA(nxt, t + 1, NAL, NAU);
        __builtin_amdgcn_s_barrier();
        asm volatile("s_waitcnt lgkmcnt(0)" ::: "memory");
        __builtin_amdgcn_sched_barrier(0);
        __builtin_amdgcn_s_setprio(1);
#pragma unroll
        for (int ks = 0; ks < 2; ks++)
#pragma unroll
            for (int mt = 0; mt < MF1; mt++)
#pragma unroll
                for (int nt = 0; nt < NF1; nt++)
                    acc[MF0 + mt][NF0 + nt] = __builtin_amdgcn_mfma_f32_16x16x32_bf16(
                        afHi[mt][ks], bfB[nt][ks], acc[MF0 + mt][NF0 + nt], 0, 0, 0);
        __builtin_amdgcn_s_setprio(0);

        // ---- P3: vmcnt(0); BAR; stage B-lower(t+2)->cur; q3 ----
        if (t + 1 < NT) {
            asm volatile("s_waitcnt vmcnt(0)" ::: "memory");
            __builtin_amdgcn_s_barrier();
            if (t + 2 < NT) stageB(cur, t + 2, 0, NBL);
        }
        __builtin_amdgcn_sched_barrier(0);
        __builtin_amdgcn_s_setprio(1);
#pragma unroll
        for (int ks = 0; ks < 2; ks++)
#pragma unroll
            for (int mt = 0; mt < MF1; mt++)
#pragma unroll
                for (int nt = 0; nt < NF0; nt++)
                    acc[MF0 + mt][nt] = __builtin_amdgcn_mfma_f32_16x16x32_bf16(
                        afHi[mt][ks], bfA[nt][ks], acc[MF0 + mt][nt], 0, 0, 0);
        __builtin_amdgcn_s_setprio(0);
    }

#pragma unroll
    for (int mt = 0; mt < MF; mt++) {
#pragma unroll
        for (int nt = 0; nt < NF; nt++) {
            long col = brow0 + wn * (BN / 4) + nt * 16 + l16;
#pragma unroll
            for (int r = 0; r < 4; r++) {
                long row = arow0 + wm * (BM / 2) + mt * 16 + quad * 4 + r;
                if (f32m) ((float*)C)[row * N + col] = acc[mt][nt][r];
                else      ((u16*)C)[row * N + col] = f2b(acc[mt][nt][r]);
            }
        }
    }
}

// ---------------------------------------------------------------------------
// gemm_p2: 2-phase GEMM with two-tile-deep staging and counted vmcnt (R4/R8
// schedule, unchanged) at <128,128>: LDS 64 KiB -> guaranteed 2 blocks/CU.
// ---------------------------------------------------------------------------
template<int BM, int BN>
__global__ __launch_bounds__(512, 4) void gemm_p2(const u16* __restrict__ A,
                                                  const u16* __restrict__ Bt,
                                                  void* __restrict__ C,
                                                  int N, int Kd,
                                                  const u16* __restrict__ xprobe) {
    constexpr int MF  = BM / 32;
    constexpr int NF  = BN / 64;
    constexpr int MF0 = MF / 2, MF1 = MF - MF0;
    constexpr int NF0 = (NF + 1) / 2, NF1 = NF - NF0;
    constexpr int NAU = BM / 64;
    constexpr int NBU = BN / 64;

    __shared__ alignas(16) u16 As[2][BM * 64];
    __shared__ alignas(16) u16 Bs[2][BN * 64];

    const bool f32m = (xprobe != nullptr) && wave_is_f32(xprobe);
    const int tid = threadIdx.x;
    const int w = tid >> 6, lane = tid & 63;
    const int wm = w >> 2, wn = w & 3;
    const int l16 = lane & 15, quad = lane >> 4;
    const long arow0 = (long)blockIdx.y * BM;
    const long brow0 = (long)blockIdx.x * BN;
    const int NT = Kd >> 6;

    const int srow = tid >> 3, scp = tid & 7;
    const long gst = (long)srow * Kd + ((scp ^ (srow & 7)) << 3);
    const int cst = tid << 3;

    const u16* Ab = A + arow0 * Kd;
    const u16* Bb = Bt + brow0 * Kd;

    auto stageA = [&](int buf, int t) {
#pragma unroll
        for (int u = 0; u < NAU; u++)
            async16(Ab + (long)u * 64 * Kd + t * 64 + gst, &As[buf][u * 4096 + cst]);
    };
    auto stageB = [&](int buf, int t) {
#pragma unroll
        for (int u = 0; u < NBU; u++)
            async16(Bb + (long)u * 64 * Kd + t * 64 + gst, &Bs[buf][u * 4096 + cst]);
    };

    const int R0a = wm * (BM / 2) + l16, sA = R0a & 7;
    const int R0b = wn * (BN / 4) + l16, sB = R0b & 7;
    int aoff[2], boff[2];
    aoff[0] = R0a * 64 + ((quad ^ sA) << 3);
    aoff[1] = R0a * 64 + (((4 + quad) ^ sA) << 3);
    boff[0] = R0b * 64 + ((quad ^ sB) << 3);
    boff[1] = R0b * 64 + (((4 + quad) ^ sB) << 3);

    f32x4 acc[MF][NF];
#pragma unroll
    for (int i = 0; i < MF; i++)
#pragma unroll
        for (int j = 0; j < NF; j++) acc[i][j] = {0.f, 0.f, 0.f, 0.f};

    stageB(0, 0); stageA(0, 0); stageB(1, 1); stageA(1, 1);
    waitvm<NAU + NBU>();
    __builtin_amdgcn_s_barrier();

#pragma unroll 1
    for (int t = 0; t < NT; ++t) {
        const int cur = t & 1;
        const u16* pA = &As[cur][0];
        const u16* pB = &Bs[cur][0];
        bf16x8 afLo[MF0][2], afHi[MF1][2], bfA[NF0][2], bfB[NF1][2];

        // ---- Phase A: read Lo set; lgkm(0); MFMA q0+q1 ----
#pragma unroll
        for (int ks = 0; ks < 2; ks++) {
#pragma unroll
            for (int mt = 0; mt < MF0; mt++)
                afLo[mt][ks] = *(const bf16x8*)&pA[aoff[ks] + mt * 1024];
#pragma unroll
            for (int nt = 0; nt < NF0; nt++)
                bfA[nt][ks] = *(const bf16x8*)&pB[boff[ks] + nt * 1024];
#pragma unroll
            for (int nt = 0; nt < NF1; nt++)
                bfB[nt][ks] = *(const bf16x8*)&pB[boff[ks] + (NF0 + nt) * 1024];
        }
        asm volatile("s_waitcnt lgkmcnt(0)" ::: "memory");
        __builtin_amdgcn_sched_barrier(0);
        __builtin_amdgcn_s_setprio(1);
#pragma unroll
        for (int ks = 0; ks < 2; ks++)
#pragma unroll
            for (int mt = 0; mt < MF0; mt++) {
#pragma unroll
                for (int nt = 0; nt < NF0; nt++)
                    acc[mt][nt] = __builtin_amdgcn_mfma_f32_16x16x32_bf16(
                        afLo[mt][ks], bfA[nt][ks], acc[mt][nt], 0, 0, 0);
#pragma unroll
                for (int nt = 0; nt < NF1; nt++)
                    acc[mt][NF0 + nt] = __builtin_amdgcn_mfma_f32_16x16x32_bf16(
                        afLo[mt][ks], bfB[nt][ks], acc[mt][NF0 + nt], 0, 0, 0);
            }
        __builtin_amdgcn_s_setprio(0);

        // ---- Phase B: read afHi; BAR; stage B(t+2); lgkm(0); MFMA q2+q3 ----
#pragma unroll
        for (int ks = 0; ks < 2; ks++)
#pragma unroll
            for (int mt = 0; mt < MF1; mt++)
                afHi[mt][ks] = *(const bf16x8*)&pA[aoff[ks] + (MF0 + mt) * 1024];
        __builtin_amdgcn_s_barrier();
        if (t + 2 < NT) stageB(cur, t + 2);
        asm volatile("s_waitcnt lgkmcnt(0)" ::: "memory");
        __builtin_amdgcn_sched_barrier(0);
        __builtin_amdgcn_s_setprio(1);
#pragma unroll
        for (int ks = 0; ks < 2; ks++)
#pragma unroll
            for (int mt = 0; mt < MF1; mt++) {
#pragma unroll
                for (int nt = 0; nt < NF1; nt++)
                    acc[MF0 + mt][NF0 + nt] = __builtin_amdgcn_mfma_f32_16x16x32_bf16(
                        afHi[mt][ks], bfB[nt][ks], acc[MF0 + mt][NF0 + nt], 0, 0, 0);
#pragma unroll
                for (int nt = 0; nt < NF0; nt++)
                    acc[MF0 + mt][nt] = __builtin_amdgcn_mfma_f32_16x16x32_bf16(
                        afHi[mt][ks], bfA[nt][ks], acc[MF0 + mt][nt], 0, 0, 0);
            }
        __builtin_amdgcn_s_setprio(0);

        // ---- tile boundary: retire tile t+1's staging; stage A(t+2) ----
        if (t + 1 < NT) {
            if (t + 2 < NT) waitvm<NBU>();
            else            waitvm<0>();
            __builtin_amdgcn_s_barrier();
            if (t + 2 < NT) stageA(cur, t + 2);
        }
    }

#pragma unroll
    for (int mt = 0; mt < MF; mt++) {
#pragma unroll
        for (int nt = 0; nt < NF; nt++) {
            long col = brow0 + wn * (BN / 4) + nt * 16 + l16;
#pragma unroll
            for (int r = 0; r < 4; r++) {
                long row = arow0 + wm * (BM / 2) + mt * 16 + quad * 4 + r;
                if (f32m) ((float*)C)[row * N + col] = acc[mt][nt][r];
                else      ((u16*)C)[row * N + col] = f2b(acc[mt][nt][r]);
            }
        }
    }
}

// ---------------------------------------------------------------------------
// RoPE(Q), RoPE(K), V-transpose in one dispatch, split by block ranges.
// V is a 64x64 LDS tile transpose (coalesced ushort4 both sides).
// Blocks: [0,16384) Q | [16384,20480) K | [20480,20992) V.
// ---------------------------------------------------------------------------
__global__ __launch_bounds__(256) void prep_k(const u16* __restrict__ QKVraw,
                                              const u16* __restrict__ cs,
                                              const u16* __restrict__ sn,
                                              u16* __restrict__ Qr,
                                              u16* __restrict__ Kr,
                                              u16* __restrict__ Vt) {
    __shared__ alignas(16) u16 tile[64 * 68];
    int bid = blockIdx.x;
    if (bid < 16384) {                       // RoPE Q -> (B,H,T,HD)
        int idx = bid * 256 + threadIdx.x;
        int d = idx & 63;
        int t = (idx >> 6) & (TT - 1);
        int bh = idx >> 16;
        long src = ((long)((bh >> 4) * TT + t)) * 3072 + (bh & 15) * HDIM;
        float u1 = b2f(QKVraw[src + d]), u2 = b2f(QKVraw[src + d + 64]);
        float c = b2f(cs[t * 64 + d]), s = b2f(sn[t * 64 + d]);
        long dst = ((long)bh * TT + t) * HDIM;
        Qr[dst + d] = f2b(u1 * c - u2 * s);
        Qr[dst + d + 64] = f2b(u1 * s + u2 * c);
    } else if (bid < 20480) {                // RoPE K -> (B,KVH,T,HD)
        int idx = (bid - 16384) * 256 + threadIdx.x;
        int d = idx & 63;
        int t = (idx >> 6) & (TT - 1);
        int bk = idx >> 16;
        long src = ((long)((bk >> 2) * TT + t)) * 3072 + 2048 + (bk & 3) * HDIM;
        float u1 = b2f(QKVraw[src + d]), u2 = b2f(QKVraw[src + d + 64]);
        float c = b2f(cs[t * 64 + d]), s = b2f(sn[t * 64 + d]);
        long dst = ((long)bk * TT + t) * HDIM;
        Kr[dst + d] = f2b(u1 * c - u2 * s);
        Kr[dst + d + 64] = f2b(u1 * s + u2 * c);
    } else {                                 // V -> (B,KVH,HD,T) via LDS transpose
        int vb = bid - 20480;                // [0,512)
        int bk = vb >> 5;                    // (b*NKV + kvh)
        int dt = (vb >> 4) & 1;              // d-tile (0..1)
        int tt = vb & 15;                    // t-tile (0..15)
        const int d0 = dt * 64, t0 = tt * 64;
        const long srcb = ((long)(bk >> 2) * TT) * 3072 + 2560 + (bk & 3) * HDIM;
#pragma unroll
        for (int i = 0; i < 4; i++) {
            int lin = i * 256 + threadIdx.x;
            int r = lin >> 4, c4 = (lin & 15) * 4;   // r = t-row, c4 = d-col
            *(ushort4*)&tile[r * 68 + c4] =
                *(const ushort4*)&QKVraw[srcb + (long)(t0 + r) * 3072 + d0 + c4];
        }
        __syncthreads();
        const long dstb = ((long)bk * 128 + d0) * 1024 + t0;
#pragma unroll
        for (int i = 0; i < 4; i++) {
            int lin = i * 256 + threadIdx.x;
            int dr = lin >> 4, c4 = (lin & 15) * 4;  // dr = d-row, c4 = t-col
            ushort4 v;
            v.x = tile[(c4 + 0) * 68 + dr];
            v.y = tile[(c4 + 1) * 68 + dr];
            v.z = tile[(c4 + 2) * 68 + dr];
            v.w = tile[(c4 + 3) * 68 + dr];
            *(ushort4*)&Vt[dstb + (long)dr * 1024 + c4] = v;
        }
    }
}

// ---------------------------------------------------------------------------
// Flash attention v6: v5 structure + T5 setprio around both MFMA clusters
// (guide: attn +4-7%) + tree-reduced softmax max/sum (serial 16-deep fmax/add
// chains -> depth-4 trees; max reassociation is exact).
// ---------------------------------------------------------------------------
__global__ __launch_bounds__(256) void attn_kernel(const u16* __restrict__ Q,
                                                   const u16* __restrict__ Kr,
                                                   const u16* __restrict__ Vt,
                                                   u16* __restrict__ O) {
    __shared__ alignas(16) u16 Ks[2][64 * 128];   // [t][d], chunk ^= row&7 (bit3 kept)
    __shared__ alignas(16) u16 Vts[2][128 * 64];  // [d][t], chunk ^= row&7
    __shared__ alignas(16) u16 Ps[64 * 88];       // [q][k], per-wave rows only

    const int tid = threadIdx.x, w = tid >> 6, lane = tid & 63;
    const int l16 = lane & 15, quad = lane >> 4;
    const float scale2 = 0.08838834764831845f * 1.4426950408889634f; // 1/sqrt(128)*log2e

#pragma unroll 1
    for (int it = 0; it < 2; it++) {
        const int j = it ? (1023 - (int)blockIdx.x) : (int)blockIdx.x;
        const int qt = 15 - (j >> 6);        // heavy first for it==0
        const int bh = j & 63;
        const int b = bh >> 4, h = bh & 15;
        const int kvh = h >> 2;
        const long qrow0 = (long)bh * TT + qt * 64;
        const long krow0 = (long)(b * NKV + kvh) * TT;
        const long vbase = ((long)(b * NKV + kvh) * HDIM) * TT;

        __syncthreads();  // prior item's LDS reads done; full drain

        // ---- stage this wave's 16 Q rows through Ks[0] (own slots only) ----
#pragma unroll
        for (int i = 0; i < 4; i++) {
            int slot0 = (w * 4 + i) * 64;
            int slot = slot0 + lane;
            int row = slot >> 4, cp = slot & 15;
            int cg = (cp & 8) | ((cp ^ row) & 7);
            async16(Q + (qrow0 + row) * HDIM + cg * 8, &Ks[0][slot0 * 8]);
        }
        asm volatile("s_waitcnt vmcnt(0)" ::: "memory");
        bf16x8 qf[4];
        {
            const int Rq = w * 16 + l16;
#pragma unroll
            for (int ds = 0; ds < 4; ds++) {
                int c = ds * 4 + quad;
                qf[ds] = *(const bf16x8*)&Ks[0][Rq * 128 + ((c & 8) | ((c ^ Rq) & 7)) * 8];
            }
        }
        asm volatile("s_waitcnt lgkmcnt(0)" ::: "memory");  // frags in regs

        // ---- prologue staging: tile0 -> buf0 (overwrites Q, own slots), tile1 -> buf1
#pragma unroll
        for (int i = 0; i < 4; i++) {
            int slot0 = (w * 4 + i) * 64;
            int slot = slot0 + lane;
            int row = slot >> 4, cp = slot & 15;
            int cg = (cp & 8) | ((cp ^ row) & 7);
            async16(Kr + (krow0 + row) * HDIM + cg * 8, &Ks[0][slot0 * 8]);
        }
#pragma unroll
        for (int i = 0; i < 4; i++) {
            int slot0 = (w * 4 + i) * 64;
            int slot = slot0 + lane;
            int row = slot >> 3, cp = slot & 7;
            int cg = cp ^ (row & 7);
            async16(Vt + vbase + (long)row * TT + cg * 8, &Vts[0][slot0 * 8]);
        }
        if (qt >= 1) {
#pragma unroll
            for (int i = 0; i < 4; i++) {
                int slot0 = (w * 4 + i) * 64;
                int slot = slot0 + lane;
                int row = slot >> 4, cp = slot & 15;
                int cg = (cp & 8) | ((cp ^ row) & 7);
                async16(Kr + (krow0 + 64 + row) * HDIM + cg * 8, &Ks[1][slot0 * 8]);
            }
#pragma unroll
            for (int i = 0; i < 4; i++) {
                int slot0 = (w * 4 + i) * 64;
                int slot = slot0 + lane;
                int row = slot >> 3, cp = slot & 7;
                int cg = cp ^ (row & 7);
                async16(Vt + vbase + (long)row * TT + 64 + cg * 8, &Vts[1][slot0 * 8]);
            }
            asm volatile("s_waitcnt vmcnt(8)" ::: "memory");  // tile0 done, tile1 in flight
        } else {
            asm volatile("s_waitcnt vmcnt(0)" ::: "memory");
        }
        asm volatile("s_barrier" ::: "memory");

        f32x4 o[8];
#pragma unroll
        for (int i = 0; i < 8; i++) o[i] = {0.f, 0.f, 0.f, 0.f};
        float m_i = -1.0e30f, l_i = 0.f;
        const int qg = qt * 64 + w * 16 + l16;

#pragma unroll 1
        for (int kt = 0; kt <= qt; kt++) {
            const int cur = kt & 1;
            const u16* ksb = Ks[cur];
            const u16* vsb = Vts[cur];

            // S^T[k][q] = sum_d K[k][d] * Q[q][d]
            f32x4 s[4];
#pragma unroll
            for (int nt = 0; nt < 4; nt++) s[nt] = {0.f, 0.f, 0.f, 0.f};
            __builtin_amdgcn_s_setprio(1);
#pragma unroll
            for (int ds = 0; ds < 4; ds++) {
                int c = ds * 4 + quad;
#pragma unroll
                for (int nt = 0; nt < 4; nt++) {
                    int Rk = nt * 16 + l16;
                    bf16x8 ak = *(const bf16x8*)&ksb[Rk * 128 + ((c & 8) | ((c ^ Rk) & 7)) * 8];
                    s[nt] = __builtin_amdgcn_mfma_f32_16x16x32_bf16(ak, qf[ds], s[nt], 0, 0, 0);
                }
            }
            __builtin_amdgcn_s_setprio(0);

            // online softmax (exp2 domain): tree-reduced max/sum + 2 shuffles
            float p[4][4];
            if (kt == qt) {
#pragma unroll
                for (int nt = 0; nt < 4; nt++)
#pragma unroll
                    for (int r = 0; r < 4; r++) {
                        int kcol = kt * 64 + nt * 16 + quad * 4 + r;
                        p[nt][r] = (kcol <= qg) ? (float)s[nt][r] * scale2 : -1.0e30f;
                    }
            } else {
#pragma unroll
                for (int nt = 0; nt < 4; nt++)
#pragma unroll
                    for (int r = 0; r < 4; r++)
                        p[nt][r] = (float)s[nt][r] * scale2;
            }
            float mrow[4];
#pragma unroll
            for (int nt = 0; nt < 4; nt++)
                mrow[nt] = fmaxf(fmaxf(p[nt][0], p[nt][1]), fmaxf(p[nt][2], p[nt][3]));
            float mx = fmaxf(fmaxf(mrow[0], mrow[1]), fmaxf(mrow[2], mrow[3]));
            mx = fmaxf(mx, __shfl_xor(mx, 16));
            mx = fmaxf(mx, __shfl_xor(mx, 32));
            float mnew = fmaxf(m_i, mx);
            float alpha = exp2f(m_i - mnew);
            float rrow[4];
#pragma unroll
            for (int nt = 0; nt < 4; nt++) {
#pragma unroll
                for (int r = 0; r < 4; r++)
                    p[nt][r] = exp2f(p[nt][r] - mnew);
                rrow[nt] = (p[nt][0] + p[nt][1]) + (p[nt][2] + p[nt][3]);
            }
            float rs = (rrow[0] + rrow[1]) + (rrow[2] + rrow[3]);
            rs += __shfl_xor(rs, 16);
            rs += __shfl_xor(rs, 32);
            l_i = l_i * alpha + rs;

            // P -> Ps (packed u32, own-wave rows)
            u32* Psw = (u32*)Ps;
            int pb = (w * 16 + l16) * 44 + quad * 2;
#pragma unroll
            for (int nt = 0; nt < 4; nt++) {
                u32 lo = (u32)f2b(p[nt][0]) | ((u32)f2b(p[nt][1]) << 16);
                u32 hi = (u32)f2b(p[nt][2]) | ((u32)f2b(p[nt][3]) << 16);
                Psw[pb + nt * 8]     = lo;
                Psw[pb + nt * 8 + 1] = hi;
            }
            if (__ballot(mnew != m_i) != 0ULL) {
#pragma unroll
                for (int n8 = 0; n8 < 8; n8++)
#pragma unroll
                    for (int r = 0; r < 4; r++) o[n8][r] *= alpha;
            }
            m_i = mnew;

            asm volatile("s_waitcnt lgkmcnt(0)" ::: "memory");  // Ps W->R, same wave

            // O^T[d][q] += V^T[d][k] * P[q][k]
            __builtin_amdgcn_s_setprio(1);
#pragma unroll
            for (int ks = 0; ks < 2; ks++) {
                bf16x8 bp = *(const bf16x8*)&Ps[(w * 16 + l16) * 88 + ks * 32 + quad * 8];
#pragma unroll
                for (int n8 = 0; n8 < 8; n8++) {
                    int Rv = n8 * 16 + l16;
                    int c = ks * 4 + quad;
                    bf16x8 av = *(const bf16x8*)&vsb[Rv * 64 + (c ^ (Rv & 7)) * 8];
                    o[n8] = __builtin_amdgcn_mfma_f32_16x16x32_bf16(av, bp, o[n8], 0, 0, 0);
                }
            }
            __builtin_amdgcn_s_setprio(0);

            if (kt == qt) break;

            // pipeline maintenance: reads of buf[cur] done -> refill it with kt+2
            asm volatile("s_waitcnt lgkmcnt(0)" ::: "memory");  // own ds_reads complete
            asm volatile("s_barrier" ::: "memory");             // all waves done with buf[cur]
            if (kt + 2 <= qt) {
                const int nk = kt + 2;
#pragma unroll
                for (int i = 0; i < 4; i++) {
                    int slot0 = (w * 4 + i) * 64;
                    int slot = slot0 + lane;
                    int row = slot >> 4, cp = slot & 15;
                    int cg = (cp & 8) | ((cp ^ row) & 7);
                    async16(Kr + (krow0 + nk * 64 + row) * HDIM + cg * 8, &Ks[cur][slot0 * 8]);
                }
#pragma unroll
                for (int i = 0; i < 4; i++) {
                    int slot0 = (w * 4 + i) * 64;
                    int slot = slot0 + lane;
                    int row = slot >> 3, cp = slot & 7;
                    int cg = cp ^ (row & 7);
                    async16(Vt + vbase + (long)row * TT + nk * 64 + cg * 8, &Vts[cur][slot0 * 8]);
                }
                asm volatile("s_waitcnt vmcnt(8)" ::: "memory");  // (kt+1)'s loads done
            } else {
                asm volatile("s_waitcnt vmcnt(0)" ::: "memory");
            }
            asm volatile("s_barrier" ::: "memory");  // buf[1-cur] ready across waves
        }

        // epilogue: normalize, pack, store this item's 64 q-rows
        float inv = 1.0f / l_i;
        long obase = ((long)(b * TT + qg)) * CDIM + h * HDIM;
#pragma unroll
        for (int n8 = 0; n8 < 8; n8++) {
            ushort4 st;
            st.x = f2b(o[n8][0] * inv);
            st.y = f2b(o[n8][1] * inv);
            st.z = f2b(o[n8][2] * inv);
            st.w = f2b(o[n8][3] * inv);
            *(ushort4*)&O[obase + n8 * 16 + quad * 4] = st;
        }
    }
}

// ---------------------------------------------------------------------------
extern "C" void kernel_launch(void* const* d_in, const int* in_sizes, int n_in,
                              void* d_out, int out_size, void* d_ws, size_t ws_size,
                              hipStream_t stream) {
    const void* x   = d_in[0];
    const void* Wq  = d_in[1];
    const void* Wkv = d_in[2];
    const void* Wo  = d_in[3];
    const void* cs  = d_in[4];
    const void* sn  = d_in[5];

    char* ws = (char*)d_ws;
    const size_t NEED = 105119748;
    if (ws_size < NEED) return;

    u16* WqkvT = (u16*)(ws + 0);          // 3072x2048 (WqT ++ WkvT)
    u16* WoT   = (u16*)(ws + 12582912);   // 2048x2048
    u16* QKVraw= (u16*)(ws + 20971520);   // 4096x3072
    u16* Qr    = (u16*)(ws + 46137344);   // (B,H,T,HD)
    u16* Kr    = (u16*)(ws + 62914560);   // (B,KVH,T,HD)
    u16* Vt    = (u16*)(ws + 67108864);   // (B,KVH,HD,T)
    u16* ATT   = (u16*)(ws + 71303168);   // 4096x2048
    u16* xb    = (u16*)(ws + 88080384);   // 4096x2048 bf16 x
    u16* csb   = (u16*)(ws + 104857600);  // 1024x64
    u16* snb   = (u16*)(ws + 104988672);  // 1024x64

    pre_k<<<10880, 256, 0, stream>>>(x, Wq, Wkv, Wo, xb, csb, snb, WqkvT, WoT, cs, sn);

    // GEMM1: 4096x3072x2048, tile 128x192, 4-phase -> grid 16x32 = 512 WGs = 2/CU
    gemm_p4<128, 192><<<dim3(16, 32), 512, 0, stream>>>(xb, WqkvT, QKVraw, 3072, 2048, nullptr);

    prep_k<<<20992, 256, 0, stream>>>(QKVraw, csb, snb, Qr, Kr, Vt);

    attn_kernel<<<512, 256, 0, stream>>>(Qr, Kr, Vt, ATT);

    // GEMM2: 4096x2048x2048, tile 128x128, 2-phase -> grid 16x32 = 512 WGs = 2/CU
    gemm_p2<128, 128><<<dim3(16, 32), 512, 0, stream>>>(ATT, WoT, d_out, 2048, 2048, (const u16*)x);
}

// Round 11
// 282.699 us; speedup vs baseline: 1.1666x; 1.0160x over previous
//
#include <hip/hip_runtime.h>

typedef unsigned short u16;
typedef unsigned int u32;
typedef __bf16 bf16x8 __attribute__((ext_vector_type(8)));
typedef float f32x4 __attribute__((ext_vector_type(4)));

#define BB   4
#define TT   1024
#define CDIM 2048
#define NH   16
#define NKV  4
#define HDIM 128

__device__ __forceinline__ float b2f(u16 u) {
    union { u32 i; float f; } x; x.i = ((u32)u) << 16; return x.f;
}
__device__ __forceinline__ u16 f2b(float f) {
    union { float f; u32 i; } x; x.f = f;
    u32 r = (x.i + 0x7fffu + ((x.i >> 16) & 1u)) >> 16;
    return (u16)r;
}
__device__ __forceinline__ void async16(const void* g, void* l) {
    __builtin_amdgcn_global_load_lds((const __attribute__((address_space(1))) void*)g,
                                     (__attribute__((address_space(3))) void*)l, 16, 0, 0);
}
template<int N> __device__ __forceinline__ void waitvm() {
    static_assert(N >= 0 && N <= 8, "unsupported vmcnt");
    if constexpr (N == 0)      asm volatile("s_waitcnt vmcnt(0)" ::: "memory");
    else if constexpr (N == 1) asm volatile("s_waitcnt vmcnt(1)" ::: "memory");
    else if constexpr (N == 2) asm volatile("s_waitcnt vmcnt(2)" ::: "memory");
    else if constexpr (N == 3) asm volatile("s_waitcnt vmcnt(3)" ::: "memory");
    else if constexpr (N == 4) asm volatile("s_waitcnt vmcnt(4)" ::: "memory");
    else if constexpr (N == 5) asm volatile("s_waitcnt vmcnt(5)" ::: "memory");
    else if constexpr (N == 6) asm volatile("s_waitcnt vmcnt(6)" ::: "memory");
    else if constexpr (N == 7) asm volatile("s_waitcnt vmcnt(7)" ::: "memory");
    else                       asm volatile("s_waitcnt vmcnt(8)" ::: "memory");
}

// Inline dtype probe: every wave samples the same 64 even u16s of x (low
// mantissa halves if fp32 -> uniform-random exponents -> ~72% implausible;
// real bf16 N(0,1) -> ~0%). Ballot => identical wave-uniform verdict everywhere.
__device__ __forceinline__ bool wave_is_f32(const u16* xp) {
    u16 v = xp[(threadIdx.x & 63) * 2];
    int e = (v >> 7) & 0xFF;
    bool bad = (v != 0) && (e < 90 || e > 160);
    return __popcll(__ballot(bad)) > 16;
}

// ---------------------------------------------------------------------------
// Fused pre-pass: convert x, cos, sin to bf16 + all three weight transposes.
// Block ranges: [0,8192) x | [8192,8256) cos | [8256,8320) sin | [8320,10880) W.
// ---------------------------------------------------------------------------
__global__ __launch_bounds__(256) void pre_k(const void* __restrict__ x,
                                             const void* __restrict__ Wq,
                                             const void* __restrict__ Wkv,
                                             const void* __restrict__ Wo,
                                             u16* __restrict__ xb,
                                             u16* __restrict__ csb,
                                             u16* __restrict__ snb,
                                             u16* __restrict__ WqkvT,
                                             u16* __restrict__ WoT,
                                             const void* __restrict__ cs,
                                             const void* __restrict__ sn) {
    const bool f32m = wave_is_f32((const u16*)x);
    int bid = blockIdx.x;
    if (bid < 8320) {                        // element-wise conversions
        const void* src; u16* dst; int i;
        if (bid < 8192)      { src = x;  dst = xb;  i = bid * 256 + threadIdx.x; }
        else if (bid < 8256) { src = cs; dst = csb; i = (bid - 8192) * 256 + threadIdx.x; }
        else                 { src = sn; dst = snb; i = (bid - 8256) * 256 + threadIdx.x; }
        union { u16 u[4]; ushort4 v; } o;
        if (f32m) {
            float4 f = ((const float4*)src)[i];
            o.u[0] = f2b(f.x); o.u[1] = f2b(f.y); o.u[2] = f2b(f.z); o.u[3] = f2b(f.w);
        } else {
            o.v = ((const ushort4*)src)[i];
        }
        ((ushort4*)dst)[i] = o.v;
        return;
    }
    // weight transpose: WT[c][r] = bf16(W[r][c])
    __shared__ alignas(16) u16 tile[64 * 65];
    int t = bid - 8320;
    const void* W; u16* WT; int rows, cols, bx, by;
    if (t < 1024)      { W = Wq;  WT = WqkvT;                    rows = 2048; cols = 2048; bx = t & 31;  by = t >> 5; }
    else if (t < 1536) { int l = t - 1024; W = Wkv; WT = WqkvT + (long)2048 * 2048; rows = 2048; cols = 1024; bx = l & 15; by = l >> 4; }
    else               { int l = t - 1536; W = Wo;  WT = WoT;  rows = 2048; cols = 2048; bx = l & 31;   by = l >> 5; }
    const int r0 = by * 64, c0 = bx * 64;
#pragma unroll
    for (int i = 0; i < 16; i++) {
        int c = threadIdx.x + i * 256;
        int rr = c >> 6, cc = c & 63;
        long idx = (long)(r0 + rr) * cols + c0 + cc;
        tile[rr * 65 + cc] = f32m ? f2b(((const float*)W)[idx]) : ((const u16*)W)[idx];
    }
    __syncthreads();
#pragma unroll
    for (int i = 0; i < 16; i++) {
        int c = threadIdx.x + i * 256;
        int rr = c >> 6, cc = c & 63;
        WT[(long)(c0 + rr) * rows + r0 + cc] = tile[cc * 65 + rr];
    }
}

// ---------------------------------------------------------------------------
// gemm_qkv: GEMM1 (xb @ WqkvT^T, 4096x3072x2048) with prep FUSED into the
// epilogue. Main loop = the proven gemm_p4 4-phase single-barrier schedule at
// BM=BN=128 (LDS 64 KiB -> 2 blocks/CU; grid 24x32 = 768 WGs). BN=128 makes
// every block's 128 output columns exactly ONE head (cb<16: Q head cb;
// cb 16-19: K kvh; cb 20-23: V kvh), so RoPE pairs (d,d+64) and the V
// transpose are block-local: acc -> bf16 -> LDS tile TB[128][129] (reuses
// As/Bs; pad 129 => conflict-free column reads) -> RoPE->Qr / RoPE->Kr /
// transpose->Vt. Eliminates prep_k and the QKVraw round-trip entirely.
// Numerics identical to the old path (f2b(acc) bf16 -> b2f -> RoPE -> f2b).
// ---------------------------------------------------------------------------
__global__ __launch_bounds__(512, 4) void gemm_qkv(const u16* __restrict__ A,
                                                   const u16* __restrict__ Bt,
                                                   const u16* __restrict__ csb,
                                                   const u16* __restrict__ snb,
                                                   u16* __restrict__ Qr,
                                                   u16* __restrict__ Kr,
                                                   u16* __restrict__ Vt,
                                                   int Kd) {
    // MF=4 NF=2 MF0=MF1=2 NF0=NF1=1 NAU=NBU=2 NAL=NBL=1
    __shared__ alignas(16) u16 smem[32768];      // As[2][8192] ++ Bs[2][8192]; TB reuses
    const int tid = threadIdx.x;
    const int w = tid >> 6, lane = tid & 63;
    const int wm = w >> 2, wn = w & 3;
    const int l16 = lane & 15, quad = lane >> 4;
    const long arow0 = (long)blockIdx.y * 128;
    const long brow0 = (long)blockIdx.x * 128;
    const int NT = Kd >> 6;

    const int srow = tid >> 3, scp = tid & 7;
    const long gst = (long)srow * Kd + ((scp ^ (srow & 7)) << 3);
    const int cst = tid << 3;

    const u16* Ab = A + arow0 * Kd;
    const u16* Bb = Bt + brow0 * Kd;

    auto As = [&](int buf) -> u16* { return smem + buf * 8192; };
    auto Bs = [&](int buf) -> u16* { return smem + 16384 + buf * 8192; };

    auto stageA = [&](int buf, int t, int u0, int u1) {
#pragma unroll
        for (int u = 0; u < 2; u++)
            if (u >= u0 && u < u1)
                async16(Ab + (long)u * 64 * Kd + t * 64 + gst, As(buf) + u * 4096 + cst);
    };
    auto stageB = [&](int buf, int t, int u0, int u1) {
#pragma unroll
        for (int u = 0; u < 2; u++)
            if (u >= u0 && u < u1)
                async16(Bb + (long)u * 64 * Kd + t * 64 + gst, Bs(buf) + u * 4096 + cst);
    };

    const int R0a = wm * 64 + l16, sA = R0a & 7;
    const int R0b = wn * 32 + l16, sB = R0b & 7;
    int aoff[2], boff[2];
    aoff[0] = R0a * 64 + ((quad ^ sA) << 3);
    aoff[1] = R0a * 64 + (((4 + quad) ^ sA) << 3);
    boff[0] = R0b * 64 + ((quad ^ sB) << 3);
    boff[1] = R0b * 64 + (((4 + quad) ^ sB) << 3);

    f32x4 acc[4][2];
#pragma unroll
    for (int i = 0; i < 4; i++)
#pragma unroll
        for (int j = 0; j < 2; j++) acc[i][j] = {0.f, 0.f, 0.f, 0.f};

    stageB(0, 0, 0, 2);
    stageA(0, 0, 0, 2);
    stageB(1, 1, 0, 1);
    waitvm<1>();
    __builtin_amdgcn_s_barrier();

#pragma unroll 1
    for (int t = 0; t < NT; ++t) {
        const int cur = t & 1, nxt = cur ^ 1;
        const u16* pA = As(cur);
        const u16* pB = Bs(cur);
        bf16x8 afLo[2][2], afHi[2][2], bfA[2], bfB[2];

        // ---- P0: read afLo+bfA; stage B-upper(t+1); BAR; q0 ----
#pragma unroll
        for (int ks = 0; ks < 2; ks++) {
#pragma unroll
            for (int mt = 0; mt < 2; mt++)
                afLo[mt][ks] = *(const bf16x8*)&pA[aoff[ks] + mt * 1024];
            bfA[ks] = *(const bf16x8*)&pB[boff[ks]];
        }
        if (t + 1 < NT) stageB(nxt, t + 1, 1, 2);
        __builtin_amdgcn_s_barrier();
        asm volatile("s_waitcnt lgkmcnt(0)" ::: "memory");
        __builtin_amdgcn_sched_barrier(0);
        __builtin_amdgcn_s_setprio(1);
#pragma unroll
        for (int ks = 0; ks < 2; ks++)
#pragma unroll
            for (int mt = 0; mt < 2; mt++)
                acc[mt][0] = __builtin_amdgcn_mfma_f32_16x16x32_bf16(
                    afLo[mt][ks], bfA[ks], acc[mt][0], 0, 0, 0);
        __builtin_amdgcn_s_setprio(0);

        // ---- P1: read bfB; stage A-lower(t+1); BAR; q1 ----
#pragma unroll
        for (int ks = 0; ks < 2; ks++)
            bfB[ks] = *(const bf16x8*)&pB[boff[ks] + 1024];
        if (t + 1 < NT) stageA(nxt, t + 1, 0, 1);
        __builtin_amdgcn_s_barrier();
        asm volatile("s_waitcnt lgkmcnt(0)" ::: "memory");
        __builtin_amdgcn_sched_barrier(0);
        __builtin_amdgcn_s_setprio(1);
#pragma unroll
        for (int ks = 0; ks < 2; ks++)
#pragma unroll
            for (int mt = 0; mt < 2; mt++)
                acc[mt][1] = __builtin_amdgcn_mfma_f32_16x16x32_bf16(
                    afLo[mt][ks], bfB[ks], acc[mt][1], 0, 0, 0);
        __builtin_amdgcn_s_setprio(0);

        // ---- P2: read afHi; stage A-upper(t+1); BAR; q2 ----
#pragma unroll
        for (int ks = 0; ks < 2; ks++)
#pragma unroll
            for (int mt = 0; mt < 2; mt++)
                afHi[mt][ks] = *(const bf16x8*)&pA[aoff[ks] + (mt + 2) * 1024];
        if (t + 1 < NT) stageA(nxt, t + 1, 1, 2);
        __builtin_amdgcn_s_barrier();
        asm volatile("s_waitcnt lgkmcnt(0)" ::: "memory");
        __builtin_amdgcn_sched_barrier(0);
        __builtin_amdgcn_s_setprio(1);
#pragma unroll
        for (int ks = 0; ks < 2; ks++)
#pragma unroll
            for (int mt = 0; mt < 2; mt++)
                acc[mt + 2][1] = __builtin_amdgcn_mfma_f32_16x16x32_bf16(
                    afHi[mt][ks], bfB[ks], acc[mt + 2][1], 0, 0, 0);
        __builtin_amdgcn_s_setprio(0);

        // ---- P3: vmcnt(0); BAR; stage B-lower(t+2)->cur; q3 ----
        if (t + 1 < NT) {
            asm volatile("s_waitcnt vmcnt(0)" ::: "memory");
            __builtin_amdgcn_s_barrier();
            if (t + 2 < NT) stageB(cur, t + 2, 0, 1);
        }
        __builtin_amdgcn_sched_barrier(0);
        __builtin_amdgcn_s_setprio(1);
#pragma unroll
        for (int ks = 0; ks < 2; ks++)
#pragma unroll
            for (int mt = 0; mt < 2; mt++)
                acc[mt + 2][0] = __builtin_amdgcn_mfma_f32_16x16x32_bf16(
                    afHi[mt][ks], bfA[ks], acc[mt + 2][0], 0, 0, 0);
        __builtin_amdgcn_s_setprio(0);
    }

    // ---- fused epilogue: acc -> TB (bf16, LDS, pad 129) -> RoPE / transpose
    constexpr int TP = 129;
    u16* TB = smem;
    __syncthreads();                         // all waves done reading As/Bs
#pragma unroll
    for (int mt = 0; mt < 4; mt++)
#pragma unroll
        for (int nt = 0; nt < 2; nt++) {
            int col = wn * 32 + nt * 16 + l16;
#pragma unroll
            for (int r = 0; r < 4; r++) {
                int row = wm * 64 + mt * 16 + quad * 4 + r;
                TB[row * TP + col] = f2b(acc[mt][nt][r]);
            }
        }
    __syncthreads();

    const int cb = blockIdx.x;
    const int b  = blockIdx.y >> 3;
    const int t0 = (blockIdx.y & 7) << 7;
    if (cb < 20) {                            // RoPE (Q: cb<16, K: 16..19)
        u16* dstp; long hb;
        if (cb < 16) { dstp = Qr; hb = (long)b * 16 + cb; }
        else         { dstp = Kr; hb = (long)b * 4 + (cb - 16); }
        const long obase = (hb * 1024 + t0) * 128;
#pragma unroll
        for (int j = 0; j < 16; j++) {
            int idx = j * 512 + tid;
            int tl = idx >> 6, d = idx & 63;
            float u1 = b2f(TB[tl * TP + d]);
            float u2 = b2f(TB[tl * TP + d + 64]);
            float c = b2f(csb[(t0 + tl) * 64 + d]);
            float s = b2f(snb[(t0 + tl) * 64 + d]);
            dstp[obase + (long)tl * 128 + d]      = f2b(u1 * c - u2 * s);
            dstp[obase + (long)tl * 128 + d + 64] = f2b(u1 * s + u2 * c);
        }
    } else {                                  // V transpose -> (B,KVH,HD,T)
        const int kvh = cb - 20;
        const long vb = ((long)(b * 4 + kvh) * 128) * 1024 + t0;
#pragma unroll
        for (int j = 0; j < 8; j++) {
            int lin = j * 512 + tid;
            int dr = lin >> 5, t4 = (lin & 31) << 2;
            ushort4 v;
            v.x = TB[(t4 + 0) * TP + dr];
            v.y = TB[(t4 + 1) * TP + dr];
            v.z = TB[(t4 + 2) * TP + dr];
            v.w = TB[(t4 + 3) * TP + dr];
            *(ushort4*)&Vt[vb + (long)dr * 1024 + t4] = v;
        }
    }
}

// ---------------------------------------------------------------------------
// gemm_p2: 2-phase GEMM with two-tile-deep staging and counted vmcnt (R4/R8
// schedule, unchanged) at <128,128>: LDS 64 KiB -> 2 blocks/CU.
// ---------------------------------------------------------------------------
template<int BM, int BN>
__global__ __launch_bounds__(512, 4) void gemm_p2(const u16* __restrict__ A,
                                                  const u16* __restrict__ Bt,
                                                  void* __restrict__ C,
                                                  int N, int Kd,
                                                  const u16* __restrict__ xprobe) {
    constexpr int MF  = BM / 32;
    constexpr int NF  = BN / 64;
    constexpr int MF0 = MF / 2, MF1 = MF - MF0;
    constexpr int NF0 = (NF + 1) / 2, NF1 = NF - NF0;
    constexpr int NAU = BM / 64;
    constexpr int NBU = BN / 64;

    __shared__ alignas(16) u16 As[2][BM * 64];
    __shared__ alignas(16) u16 Bs[2][BN * 64];

    const bool f32m = (xprobe != nullptr) && wave_is_f32(xprobe);
    const int tid = threadIdx.x;
    const int w = tid >> 6, lane = tid & 63;
    const int wm = w >> 2, wn = w & 3;
    const int l16 = lane & 15, quad = lane >> 4;
    const long arow0 = (long)blockIdx.y * BM;
    const long brow0 = (long)blockIdx.x * BN;
    const int NT = Kd >> 6;

    const int srow = tid >> 3, scp = tid & 7;
    const long gst = (long)srow * Kd + ((scp ^ (srow & 7)) << 3);
    const int cst = tid << 3;

    const u16* Ab = A + arow0 * Kd;
    const u16* Bb = Bt + brow0 * Kd;

    auto stageA = [&](int buf, int t) {
#pragma unroll
        for (int u = 0; u < NAU; u++)
            async16(Ab + (long)u * 64 * Kd + t * 64 + gst, &As[buf][u * 4096 + cst]);
    };
    auto stageB = [&](int buf, int t) {
#pragma unroll
        for (int u = 0; u < NBU; u++)
            async16(Bb + (long)u * 64 * Kd + t * 64 + gst, &Bs[buf][u * 4096 + cst]);
    };

    const int R0a = wm * (BM / 2) + l16, sA = R0a & 7;
    const int R0b = wn * (BN / 4) + l16, sB = R0b & 7;
    int aoff[2], boff[2];
    aoff[0] = R0a * 64 + ((quad ^ sA) << 3);
    aoff[1] = R0a * 64 + (((4 + quad) ^ sA) << 3);
    boff[0] = R0b * 64 + ((quad ^ sB) << 3);
    boff[1] = R0b * 64 + (((4 + quad) ^ sB) << 3);

    f32x4 acc[MF][NF];
#pragma unroll
    for (int i = 0; i < MF; i++)
#pragma unroll
        for (int j = 0; j < NF; j++) acc[i][j] = {0.f, 0.f, 0.f, 0.f};

    stageB(0, 0); stageA(0, 0); stageB(1, 1); stageA(1, 1);
    waitvm<NAU + NBU>();
    __builtin_amdgcn_s_barrier();

#pragma unroll 1
    for (int t = 0; t < NT; ++t) {
        const int cur = t & 1;
        const u16* pA = &As[cur][0];
        const u16* pB = &Bs[cur][0];
        bf16x8 afLo[MF0][2], afHi[MF1][2], bfA[NF0][2], bfB[NF1][2];

        // ---- Phase A: read Lo set; lgkm(0); MFMA q0+q1 ----
#pragma unroll
        for (int ks = 0; ks < 2; ks++) {
#pragma unroll
            for (int mt = 0; mt < MF0; mt++)
                afLo[mt][ks] = *(const bf16x8*)&pA[aoff[ks] + mt * 1024];
#pragma unroll
            for (int nt = 0; nt < NF0; nt++)
                bfA[nt][ks] = *(const bf16x8*)&pB[boff[ks] + nt * 1024];
#pragma unroll
            for (int nt = 0; nt < NF1; nt++)
                bfB[nt][ks] = *(const bf16x8*)&pB[boff[ks] + (NF0 + nt) * 1024];
        }
        asm volatile("s_waitcnt lgkmcnt(0)" ::: "memory");
        __builtin_amdgcn_sched_barrier(0);
        __builtin_amdgcn_s_setprio(1);
#pragma unroll
        for (int ks = 0; ks < 2; ks++)
#pragma unroll
            for (int mt = 0; mt < MF0; mt++) {
#pragma unroll
                for (int nt = 0; nt < NF0; nt++)
                    acc[mt][nt] = __builtin_amdgcn_mfma_f32_16x16x32_bf16(
                        afLo[mt][ks], bfA[nt][ks], acc[mt][nt], 0, 0, 0);
#pragma unroll
                for (int nt = 0; nt < NF1; nt++)
                    acc[mt][NF0 + nt] = __builtin_amdgcn_mfma_f32_16x16x32_bf16(
                        afLo[mt][ks], bfB[nt][ks], acc[mt][NF0 + nt], 0, 0, 0);
            }
        __builtin_amdgcn_s_setprio(0);

        // ---- Phase B: read afHi; BAR; stage B(t+2); lgkm(0); MFMA q2+q3 ----
#pragma unroll
        for (int ks = 0; ks < 2; ks++)
#pragma unroll
            for (int mt = 0; mt < MF1; mt++)
                afHi[mt][ks] = *(const bf16x8*)&pA[aoff[ks] + (MF0 + mt) * 1024];
        __builtin_amdgcn_s_barrier();
        if (t + 2 < NT) stageB(cur, t + 2);
        asm volatile("s_waitcnt lgkmcnt(0)" ::: "memory");
        __builtin_amdgcn_sched_barrier(0);
        __builtin_amdgcn_s_setprio(1);
#pragma unroll
        for (int ks = 0; ks < 2; ks++)
#pragma unroll
            for (int mt = 0; mt < MF1; mt++) {
#pragma unroll
                for (int nt = 0; nt < NF1; nt++)
                    acc[MF0 + mt][NF0 + nt] = __builtin_amdgcn_mfma_f32_16x16x32_bf16(
                        afHi[mt][ks], bfB[nt][ks], acc[MF0 + mt][NF0 + nt], 0, 0, 0);
#pragma unroll
                for (int nt = 0; nt < NF0; nt++)
                    acc[MF0 + mt][nt] = __builtin_amdgcn_mfma_f32_16x16x32_bf16(
                        afHi[mt][ks], bfA[nt][ks], acc[MF0 + mt][nt], 0, 0, 0);
            }
        __builtin_amdgcn_s_setprio(0);

        // ---- tile boundary: retire tile t+1's staging; stage A(t+2) ----
        if (t + 1 < NT) {
            if (t + 2 < NT) waitvm<NBU>();
            else            waitvm<0>();
            __builtin_amdgcn_s_barrier();
            if (t + 2 < NT) stageA(cur, t + 2);
        }
    }

#pragma unroll
    for (int mt = 0; mt < MF; mt++) {
#pragma unroll
        for (int nt = 0; nt < NF; nt++) {
            long col = brow0 + wn * (BN / 4) + nt * 16 + l16;
#pragma unroll
            for (int r = 0; r < 4; r++) {
                long row = arow0 + wm * (BM / 2) + mt * 16 + quad * 4 + r;
                if (f32m) ((float*)C)[row * N + col] = acc[mt][nt][r];
                else      ((u16*)C)[row * N + col] = f2b(acc[mt][nt][r]);
            }
        }
    }
}

// ---------------------------------------------------------------------------
// Flash attention v6: v5 structure + T5 setprio around both MFMA clusters
// + tree-reduced softmax max/sum.
// ---------------------------------------------------------------------------
__global__ __launch_bounds__(256) void attn_kernel(const u16* __restrict__ Q,
                                                   const u16* __restrict__ Kr,
                                                   const u16* __restrict__ Vt,
                                                   u16* __restrict__ O) {
    __shared__ alignas(16) u16 Ks[2][64 * 128];   // [t][d], chunk ^= row&7 (bit3 kept)
    __shared__ alignas(16) u16 Vts[2][128 * 64];  // [d][t], chunk ^= row&7
    __shared__ alignas(16) u16 Ps[64 * 88];       // [q][k], per-wave rows only

    const int tid = threadIdx.x, w = tid >> 6, lane = tid & 63;
    const int l16 = lane & 15, quad = lane >> 4;
    const float scale2 = 0.08838834764831845f * 1.4426950408889634f; // 1/sqrt(128)*log2e

#pragma unroll 1
    for (int it = 0; it < 2; it++) {
        const int j = it ? (1023 - (int)blockIdx.x) : (int)blockIdx.x;
        const int qt = 15 - (j >> 6);        // heavy first for it==0
        const int bh = j & 63;
        const int b = bh >> 4, h = bh & 15;
        const int kvh = h >> 2;
        const long qrow0 = (long)bh * TT + qt * 64;
        const long krow0 = (long)(b * NKV + kvh) * TT;
        const long vbase = ((long)(b * NKV + kvh) * HDIM) * TT;

        __syncthreads();  // prior item's LDS reads done; full drain

        // ---- stage this wave's 16 Q rows through Ks[0] (own slots only) ----
#pragma unroll
        for (int i = 0; i < 4; i++) {
            int slot0 = (w * 4 + i) * 64;
            int slot = slot0 + lane;
            int row = slot >> 4, cp = slot & 15;
            int cg = (cp & 8) | ((cp ^ row) & 7);
            async16(Q + (qrow0 + row) * HDIM + cg * 8, &Ks[0][slot0 * 8]);
        }
        asm volatile("s_waitcnt vmcnt(0)" ::: "memory");
        bf16x8 qf[4];
        {
            const int Rq = w * 16 + l16;
#pragma unroll
            for (int ds = 0; ds < 4; ds++) {
                int c = ds * 4 + quad;
                qf[ds] = *(const bf16x8*)&Ks[0][Rq * 128 + ((c & 8) | ((c ^ Rq) & 7)) * 8];
            }
        }
        asm volatile("s_waitcnt lgkmcnt(0)" ::: "memory");  // frags in regs

        // ---- prologue staging: tile0 -> buf0 (overwrites Q, own slots), tile1 -> buf1
#pragma unroll
        for (int i = 0; i < 4; i++) {
            int slot0 = (w * 4 + i) * 64;
            int slot = slot0 + lane;
            int row = slot >> 4, cp = slot & 15;
            int cg = (cp & 8) | ((cp ^ row) & 7);
            async16(Kr + (krow0 + row) * HDIM + cg * 8, &Ks[0][slot0 * 8]);
        }
#pragma unroll
        for (int i = 0; i < 4; i++) {
            int slot0 = (w * 4 + i) * 64;
            int slot = slot0 + lane;
            int row = slot >> 3, cp = slot & 7;
            int cg = cp ^ (row & 7);
            async16(Vt + vbase + (long)row * TT + cg * 8, &Vts[0][slot0 * 8]);
        }
        if (qt >= 1) {
#pragma unroll
            for (int i = 0; i < 4; i++) {
                int slot0 = (w * 4 + i) * 64;
                int slot = slot0 + lane;
                int row = slot >> 4, cp = slot & 15;
                int cg = (cp & 8) | ((cp ^ row) & 7);
                async16(Kr + (krow0 + 64 + row) * HDIM + cg * 8, &Ks[1][slot0 * 8]);
            }
#pragma unroll
            for (int i = 0; i < 4; i++) {
                int slot0 = (w * 4 + i) * 64;
                int slot = slot0 + lane;
                int row = slot >> 3, cp = slot & 7;
                int cg = cp ^ (row & 7);
                async16(Vt + vbase + (long)row * TT + 64 + cg * 8, &Vts[1][slot0 * 8]);
            }
            asm volatile("s_waitcnt vmcnt(8)" ::: "memory");  // tile0 done, tile1 in flight
        } else {
            asm volatile("s_waitcnt vmcnt(0)" ::: "memory");
        }
        asm volatile("s_barrier" ::: "memory");

        f32x4 o[8];
#pragma unroll
        for (int i = 0; i < 8; i++) o[i] = {0.f, 0.f, 0.f, 0.f};
        float m_i = -1.0e30f, l_i = 0.f;
        const int qg = qt * 64 + w * 16 + l16;

#pragma unroll 1
        for (int kt = 0; kt <= qt; kt++) {
            const int cur = kt & 1;
            const u16* ksb = Ks[cur];
            const u16* vsb = Vts[cur];

            // S^T[k][q] = sum_d K[k][d] * Q[q][d]
            f32x4 s[4];
#pragma unroll
            for (int nt = 0; nt < 4; nt++) s[nt] = {0.f, 0.f, 0.f, 0.f};
            __builtin_amdgcn_s_setprio(1);
#pragma unroll
            for (int ds = 0; ds < 4; ds++) {
                int c = ds * 4 + quad;
#pragma unroll
                for (int nt = 0; nt < 4; nt++) {
                    int Rk = nt * 16 + l16;
                    bf16x8 ak = *(const bf16x8*)&ksb[Rk * 128 + ((c & 8) | ((c ^ Rk) & 7)) * 8];
                    s[nt] = __builtin_amdgcn_mfma_f32_16x16x32_bf16(ak, qf[ds], s[nt], 0, 0, 0);
                }
            }
            __builtin_amdgcn_s_setprio(0);

            // online softmax (exp2 domain): tree-reduced max/sum + 2 shuffles
            float p[4][4];
            if (kt == qt) {
#pragma unroll
                for (int nt = 0; nt < 4; nt++)
#pragma unroll
                    for (int r = 0; r < 4; r++) {
                        int kcol = kt * 64 + nt * 16 + quad * 4 + r;
                        p[nt][r] = (kcol <= qg) ? (float)s[nt][r] * scale2 : -1.0e30f;
                    }
            } else {
#pragma unroll
                for (int nt = 0; nt < 4; nt++)
#pragma unroll
                    for (int r = 0; r < 4; r++)
                        p[nt][r] = (float)s[nt][r] * scale2;
            }
            float mrow[4];
#pragma unroll
            for (int nt = 0; nt < 4; nt++)
                mrow[nt] = fmaxf(fmaxf(p[nt][0], p[nt][1]), fmaxf(p[nt][2], p[nt][3]));
            float mx = fmaxf(fmaxf(mrow[0], mrow[1]), fmaxf(mrow[2], mrow[3]));
            mx = fmaxf(mx, __shfl_xor(mx, 16));
            mx = fmaxf(mx, __shfl_xor(mx, 32));
            float mnew = fmaxf(m_i, mx);
            float alpha = exp2f(m_i - mnew);
            float rrow[4];
#pragma unroll
            for (int nt = 0; nt < 4; nt++) {
#pragma unroll
                for (int r = 0; r < 4; r++)
                    p[nt][r] = exp2f(p[nt][r] - mnew);
                rrow[nt] = (p[nt][0] + p[nt][1]) + (p[nt][2] + p[nt][3]);
            }
            float rs = (rrow[0] + rrow[1]) + (rrow[2] + rrow[3]);
            rs += __shfl_xor(rs, 16);
            rs += __shfl_xor(rs, 32);
            l_i = l_i * alpha + rs;

            // P -> Ps (packed u32, own-wave rows)
            u32* Psw = (u32*)Ps;
            int pb = (w * 16 + l16) * 44 + quad * 2;
#pragma unroll
            for (int nt = 0; nt < 4; nt++) {
                u32 lo = (u32)f2b(p[nt][0]) | ((u32)f2b(p[nt][1]) << 16);
                u32 hi = (u32)f2b(p[nt][2]) | ((u32)f2b(p[nt][3]) << 16);
                Psw[pb + nt * 8]     = lo;
                Psw[pb + nt * 8 + 1] = hi;
            }
            if (__ballot(mnew != m_i) != 0ULL) {
#pragma unroll
                for (int n8 = 0; n8 < 8; n8++)
#pragma unroll
                    for (int r = 0; r < 4; r++) o[n8][r] *= alpha;
            }
            m_i = mnew;

            asm volatile("s_waitcnt lgkmcnt(0)" ::: "memory");  // Ps W->R, same wave

            // O^T[d][q] += V^T[d][k] * P[q][k]
            __builtin_amdgcn_s_setprio(1);
#pragma unroll
            for (int ks = 0; ks < 2; ks++) {
                bf16x8 bp = *(const bf16x8*)&Ps[(w * 16 + l16) * 88 + ks * 32 + quad * 8];
#pragma unroll
                for (int n8 = 0; n8 < 8; n8++) {
                    int Rv = n8 * 16 + l16;
                    int c = ks * 4 + quad;
                    bf16x8 av = *(const bf16x8*)&vsb[Rv * 64 + (c ^ (Rv & 7)) * 8];
                    o[n8] = __builtin_amdgcn_mfma_f32_16x16x32_bf16(av, bp, o[n8], 0, 0, 0);
                }
            }
            __builtin_amdgcn_s_setprio(0);

            if (kt == qt) break;

            // pipeline maintenance: reads of buf[cur] done -> refill it with kt+2
            asm volatile("s_waitcnt lgkmcnt(0)" ::: "memory");  // own ds_reads complete
            asm volatile("s_barrier" ::: "memory");             // all waves done with buf[cur]
            if (kt + 2 <= qt) {
                const int nk = kt + 2;
#pragma unroll
                for (int i = 0; i < 4; i++) {
                    int slot0 = (w * 4 + i) * 64;
                    int slot = slot0 + lane;
                    int row = slot >> 4, cp = slot & 15;
                    int cg = (cp & 8) | ((cp ^ row) & 7);
                    async16(Kr + (krow0 + nk * 64 + row) * HDIM + cg * 8, &Ks[cur][slot0 * 8]);
                }
#pragma unroll
                for (int i = 0; i < 4; i++) {
                    int slot0 = (w * 4 + i) * 64;
                    int slot = slot0 + lane;
                    int row = slot >> 3, cp = slot & 7;
                    int cg = cp ^ (row & 7);
                    async16(Vt + vbase + (long)row * TT + nk * 64 + cg * 8, &Vts[cur][slot0 * 8]);
                }
                asm volatile("s_waitcnt vmcnt(8)" ::: "memory");  // (kt+1)'s loads done
            } else {
                asm volatile("s_waitcnt vmcnt(0)" ::: "memory");
            }
            asm volatile("s_barrier" ::: "memory");  // buf[1-cur] ready across waves
        }

        // epilogue: normalize, pack, store this item's 64 q-rows
        float inv = 1.0f / l_i;
        long obase = ((long)(b * TT + qg)) * CDIM + h * HDIM;
#pragma unroll
        for (int n8 = 0; n8 < 8; n8++) {
            ushort4 st;
            st.x = f2b(o[n8][0] * inv);
            st.y = f2b(o[n8][1] * inv);
            st.z = f2b(o[n8][2] * inv);
            st.w = f2b(o[n8][3] * inv);
            *(ushort4*)&O[obase + n8 * 16 + quad * 4] = st;
        }
    }
}

// ---------------------------------------------------------------------------
extern "C" void kernel_launch(void* const* d_in, const int* in_sizes, int n_in,
                              void* d_out, int out_size, void* d_ws, size_t ws_size,
                              hipStream_t stream) {
    const void* x   = d_in[0];
    const void* Wq  = d_in[1];
    const void* Wkv = d_in[2];
    const void* Wo  = d_in[3];
    const void* cs  = d_in[4];
    const void* sn  = d_in[5];

    char* ws = (char*)d_ws;
    const size_t NEED = 105119748;
    if (ws_size < NEED) return;

    u16* WqkvT = (u16*)(ws + 0);          // 3072x2048 (WqT ++ WkvT)
    u16* WoT   = (u16*)(ws + 12582912);   // 2048x2048
    u16* Qr    = (u16*)(ws + 46137344);   // (B,H,T,HD)
    u16* Kr    = (u16*)(ws + 62914560);   // (B,KVH,T,HD)
    u16* Vt    = (u16*)(ws + 67108864);   // (B,KVH,HD,T)
    u16* ATT   = (u16*)(ws + 71303168);   // 4096x2048
    u16* xb    = (u16*)(ws + 88080384);   // 4096x2048 bf16 x
    u16* csb   = (u16*)(ws + 104857600);  // 1024x64
    u16* snb   = (u16*)(ws + 104988672);  // 1024x64

    pre_k<<<10880, 256, 0, stream>>>(x, Wq, Wkv, Wo, xb, csb, snb, WqkvT, WoT, cs, sn);

    // GEMM1 + fused RoPE/V-transpose: 4096x3072x2048, tile 128x128,
    // grid 24x32 = 768 WGs = 2/CU resident (64 KiB LDS); writes Qr/Kr/Vt.
    gemm_qkv<<<dim3(24, 32), 512, 0, stream>>>(xb, WqkvT, csb, snb, Qr, Kr, Vt, 2048);

    attn_kernel<<<512, 256, 0, stream>>>(Qr, Kr, Vt, ATT);

    // GEMM2: 4096x2048x2048, tile 128x128, 2-phase -> grid 16x32 = 512 WGs = 2/CU
    gemm_p2<128, 128><<<dim3(16, 32), 512, 0, stream>>>(ATT, WoT, d_out, 2048, 2048, (const u16*)x);
}